// Round 8
// baseline (508.628 us; speedup 1.0000x reference)
//
#include <hip/hip_runtime.h>

#define NPTS   65536
#define NB     2048
#define DIMX   256
#define HIDN   512
#define MAXNN  64
#define MIDK   288
#define MIDV   384
#define MIDD   384
#define MIDS   256

typedef unsigned short ushort_t;
typedef __attribute__((ext_vector_type(8))) short short8;
typedef __attribute__((ext_vector_type(4))) float f32x4;

// ---------------- helpers ----------------
// mish(x) = x*tanh(softplus(x)) = x * e(e+2)/(e(e+2)+2), e = exp(x)  [exact identity]
__device__ __forceinline__ float mishf(float x) {
    float e = __expf(fminf(x, 30.f));
    float n = e * (e + 2.f);
    return x * n * __builtin_amdgcn_rcpf(n + 2.f);
}
__device__ __forceinline__ ushort_t f2bf(float f) {
    unsigned u = __float_as_uint(f);
    u += 0x7fffu + ((u >> 16) & 1u);
    return (ushort_t)(u >> 16);
}
__device__ __forceinline__ float bf2f(ushort_t h) {
    return __uint_as_float(((unsigned)h) << 16);
}
__device__ __forceinline__ void dma16(const void* g, void* lds) {
    __builtin_amdgcn_global_load_lds(
        (const __attribute__((address_space(1))) unsigned int*)g,
        (__attribute__((address_space(3))) unsigned int*)lds, 16, 0, 0);
}
__device__ __forceinline__ int lbound(const int* __restrict__ a, int lo, int hi, int v) {
    while (lo < hi) { int m = (lo + hi) >> 1; if (a[m] < v) lo = m + 1; else hi = m; }
    return lo;
}

// ---------------- small kernels ----------------
__global__ __launch_bounds__(256)
void k_mag(const float* __restrict__ x, const float* __restrict__ rW,
           const float* __restrict__ rb, float* __restrict__ mag,
           unsigned int* __restrict__ maxmag, ushort_t* __restrict__ xb)
{
    const int lane = threadIdx.x & 63;
    const int wave = threadIdx.x >> 6;
    const int gw = blockIdx.x * 4 + wave;   // 16384 waves
    float4 wv = *(const float4*)(rW + lane * 4);
    float bias = rb[0];
    float lmax = 0.f;
    for (int pt = gw; pt < NPTS; pt += 16384) {
        float4 xv = *(const float4*)(x + (size_t)pt * DIMX + lane * 4);
        ushort4 u;
        u.x = f2bf(xv.x); u.y = f2bf(xv.y); u.z = f2bf(xv.z); u.w = f2bf(xv.w);
        *(ushort4*)(xb + (size_t)pt * DIMX + lane * 4) = u;
        double d = (double)xv.x * wv.x + (double)xv.y * wv.y
                 + (double)xv.z * wv.z + (double)xv.w * wv.w;
        #pragma unroll
        for (int o = 32; o > 0; o >>= 1) d += __shfl_xor(d, o);
        float s = fabsf((float)(d + (double)bias));
        if (lane == 0) mag[pt] = s;
        lmax = fmaxf(lmax, s);
    }
    __shared__ float wm[4];
    if (lane == 0) wm[wave] = lmax;
    __syncthreads();
    if (threadIdx.x == 0) {
        float m = fmaxf(fmaxf(wm[0], wm[1]), fmaxf(wm[2], wm[3]));
        atomicMax(maxmag, __float_as_uint(m));
    }
}

__global__ __launch_bounds__(256)
void k_rank(const int* __restrict__ batch, const float* __restrict__ mag,
            const unsigned int* __restrict__ maxmag, int* __restrict__ kidx)
{
    int i = blockIdx.x * 256 + threadIdx.x;
    if (i >= NPTS) return;
    int b = batch[i];
    int s = lbound(batch, 0, NPTS, b);
    int e = lbound(batch, s, NPTS, b + 1);
    float M = __uint_as_float(*maxmag);
    float kb = __fmul_rn((float)b, M);
    float ki = __fadd_rn(kb, mag[i]);
    int r = 0;
    for (int j = s; j < e; ++j) {
        float kj = __fadd_rn(kb, mag[j]);
        r += (kj < ki) || (kj == ki && j < i);
    }
    kidx[i] = (r < MAXNN) ? r : MAXNN;
}

// merged setup: blocks 0..128 key tables; 129..2176 card-init of z; rest wt; blk0 inits maxmag
__global__ __launch_bounds__(512)
void k_setup(const float* __restrict__ eW1, const float* __restrict__ eb1,
             const float* __restrict__ eg, const float* __restrict__ ebe,
             const float* __restrict__ eW2, const float* __restrict__ eb2,
             const float* __restrict__ dW1, const float* __restrict__ db1,
             const float* __restrict__ dg, const float* __restrict__ dbe,
             const float* __restrict__ dW2, const float* __restrict__ db2,
             float* __restrict__ enc_tbl, float* __restrict__ dec_tbl,
             const int* __restrict__ batch, const float* __restrict__ cardW,
             const float* __restrict__ cardb, float* __restrict__ z,
             const float* __restrict__ V0, ushort_t* __restrict__ T0,
             const float* __restrict__ V1, ushort_t* __restrict__ T1,
             const float* __restrict__ V2, ushort_t* __restrict__ T2,
             const float* __restrict__ V3, ushort_t* __restrict__ T3,
             unsigned int* __restrict__ maxmag)
{
    const int blk = blockIdx.x;
    const int t = threadIdx.x;
    if (blk == 0 && t == 0) *maxmag = 0u;
    if (blk < 129) {
        const float *W1, *b1, *g, *be, *W2, *b2; float* out; int wrow;
        if (blk < 65) {
            W1 = eW1; b1 = eb1; g = eg; be = ebe; W2 = eW2; b2 = eb2;
            out = enc_tbl + blk * HIDN; wrow = (blk < 64) ? blk : -1;
        } else {
            int r = blk - 65;
            W1 = dW1; b1 = db1; g = dg; be = dbe; W2 = dW2; b2 = db2;
            out = dec_tbl + r * HIDN; wrow = r;
        }
        __shared__ float h[MIDK];
        __shared__ float red[512];
        float v = 0.f;
        if (t < MIDK) v = b1[t] + (wrow >= 0 ? W1[wrow * MIDK + t] : 0.f);
        red[t] = (t < MIDK) ? v : 0.f;
        __syncthreads();
        for (int o = 256; o > 0; o >>= 1) { if (t < o) red[t] += red[t + o]; __syncthreads(); }
        float m = red[0] / (float)MIDK;
        __syncthreads();
        float d = v - m;
        red[t] = (t < MIDK) ? d * d : 0.f;
        __syncthreads();
        for (int o = 256; o > 0; o >>= 1) { if (t < o) red[t] += red[t + o]; __syncthreads(); }
        float rs = rsqrtf(red[0] / (float)MIDK + 1e-5f);
        __syncthreads();
        if (t < MIDK) h[t] = mishf(d * rs * g[t] + be[t]);
        __syncthreads();
        float acc = b2[t];
        #pragma unroll 8
        for (int k = 0; k < MIDK; ++k) acc = fmaf(h[k], W2[k * HIDN + t], acc);
        out[t] = acc;
    } else if (blk < 129 + NB) {
        int b = blk - 129;
        int s = lbound(batch, 0, NPTS, b);
        int e = lbound(batch, s, NPTS, b + 1);
        float n = (float)(e - s);
        z[b * HIDN + t] = fmaf(n, cardW[t], cardb[t]);
    } else {
        int idx = (blk - (129 + NB)) * 512 + t;
        const float* W; ushort_t* T; int N, K, off;
        if (idx < 98304)       { W = V0; T = T0; K = 256; N = 384; off = idx; }
        else if (idx < 294912) { W = V1; T = T1; K = 384; N = 512; off = idx - 98304; }
        else if (idx < 491520) { W = V2; T = T2; K = 512; N = 384; off = idx - 294912; }
        else                   { W = V3; T = T3; K = 384; N = 256; off = idx - 491520; }
        int k = off / N, n = off - k * N;
        T[(size_t)n * K + k] = f2bf(W[off]);
    }
}

// d_size MLP: 4 batches per block (4x W1 reuse)
__global__ __launch_bounds__(256)
void k_size(const float* __restrict__ z, const float* __restrict__ W1,
            const float* __restrict__ b1, const float* __restrict__ g,
            const float* __restrict__ be, const float* __restrict__ W2,
            const float* __restrict__ b2, int* __restrict__ ndec)
{
    const int b0 = blockIdx.x * 4, t = threadIdx.x;
    __shared__ float zr[4][HIDN];
    __shared__ float red[4][256];
    #pragma unroll
    for (int gI = 0; gI < 4; ++gI) {
        zr[gI][t] = z[(b0 + gI) * HIDN + t];
        zr[gI][t + 256] = z[(b0 + gI) * HIDN + 256 + t];
    }
    __syncthreads();
    float acc[4];
    float bb1 = b1[t];
    #pragma unroll
    for (int gI = 0; gI < 4; ++gI) acc[gI] = bb1;
    #pragma unroll 8
    for (int k = 0; k < HIDN; ++k) {
        float wv = W1[k * MIDS + t];
        #pragma unroll
        for (int gI = 0; gI < 4; ++gI) acc[gI] = fmaf(zr[gI][k], wv, acc[gI]);
    }
    #pragma unroll
    for (int gI = 0; gI < 4; ++gI) red[gI][t] = acc[gI];
    __syncthreads();
    for (int o = 128; o > 0; o >>= 1) {
        if (t < o) {
            #pragma unroll
            for (int gI = 0; gI < 4; ++gI) red[gI][t] += red[gI][t + o];
        }
        __syncthreads();
    }
    float mm[4];
    #pragma unroll
    for (int gI = 0; gI < 4; ++gI) mm[gI] = red[gI][0] * (1.f / 256.f);
    __syncthreads();
    #pragma unroll
    for (int gI = 0; gI < 4; ++gI) { float d = acc[gI] - mm[gI]; red[gI][t] = d * d; }
    __syncthreads();
    for (int o = 128; o > 0; o >>= 1) {
        if (t < o) {
            #pragma unroll
            for (int gI = 0; gI < 4; ++gI) red[gI][t] += red[gI][t + o];
        }
        __syncthreads();
    }
    float rs[4];
    #pragma unroll
    for (int gI = 0; gI < 4; ++gI) rs[gI] = rsqrtf(red[gI][0] * (1.f / 256.f) + 1e-5f);
    __syncthreads();
    float w2 = W2[t], gg = g[t], bbe = be[t];
    #pragma unroll
    for (int gI = 0; gI < 4; ++gI) {
        float h = mishf((acc[gI] - mm[gI]) * rs[gI] * gg + bbe);
        red[gI][t] = h * w2;
    }
    __syncthreads();
    for (int o = 128; o > 0; o >>= 1) {
        if (t < o) {
            #pragma unroll
            for (int gI = 0; gI < 4; ++gI) red[gI][t] += red[gI][t + o];
        }
        __syncthreads();
    }
    if (t < 4) {
        float logit = red[t][0] + b2[0];
        float n = rintf(logit);
        n = fminf(fmaxf(n, 0.f), 64.f);
        ndec[b0 + t] = (int)n;
    }
}

// zero out_x + write batch_out/mask + (block 0) compact+pad. grid 1024x256.
__global__ __launch_bounds__(256)
void k_post(const int* __restrict__ ndec, float* __restrict__ out_x,
            float* __restrict__ outb, float* __restrict__ outm,
            int* __restrict__ rowmap, int* __restrict__ cntpad)
{
    const int gidx = blockIdx.x * 256 + threadIdx.x;
    float4 z4 = make_float4(0.f, 0.f, 0.f, 0.f);
    float4* p = (float4*)out_x;
    #pragma unroll
    for (int i = 0; i < 32; ++i) p[gidx + i * 262144] = z4;
    if (gidx < NB * MAXNN) {
        outb[gidx] = (float)(gidx >> 6);
        outm[gidx] = ((gidx & 63) < ndec[gidx >> 6]) ? 1.f : 0.f;
    }
    if (blockIdx.x == 0) {
        __shared__ int lcnt;
        if (threadIdx.x == 0) lcnt = 0;
        __syncthreads();
        for (int b = threadIdx.x; b < NB; b += 256) {
            int n = ndec[b];
            if (n > 0) {
                int base = atomicAdd(&lcnt, n);
                for (int q = 0; q < n; ++q) rowmap[base + q] = b * 64 + q;
            }
        }
        __syncthreads();
        int c = lcnt;
        int pad = (c + 127) & ~127;
        for (int i = c + threadIdx.x; i < pad; i += 256) rowmap[i] = -1;
        if (threadIdx.x == 0) *cntpad = pad;
    }
}

// ---------------- fused encoder, 64-row tiles, 80KB LDS (2 blocks/CU) ----------------
// phase A: Hslab(64x384) = bf16(mish(LN(xb @ W1t + b1))) -> LDS (6 xor panels),
//          B streamed in two 192-col halves (staging 32KB).
// phase B: y = (Hslab @ W2t + b2) * enc_tbl[kidx]; 4 n-tiles of 128; segmented scan.
__global__ __launch_bounds__(512, 4)
void k_enc(const ushort_t* __restrict__ A, const ushort_t* __restrict__ B1t,
           const float* __restrict__ b1, const float* __restrict__ g,
           const float* __restrict__ be, const ushort_t* __restrict__ B2t,
           const float* __restrict__ b2, const float* __restrict__ tbl,
           const int* __restrict__ kidx, const int* __restrict__ batch,
           float* __restrict__ zout)
{
    const int m0 = blockIdx.x * 64;
    __shared__ __align__(16) char SMEM[81920];
    ushort_t* slab = (ushort_t*)SMEM;            // 6 panels * 64r*64k bf16 = 48KB
    ushort_t* As   = (ushort_t*)(SMEM + 49152);  // 64x64 bf16 (8KB)
    ushort_t* Bs   = (ushort_t*)(SMEM + 57344);  // 192x64 bf16 (24KB)
    ushort_t* Bs2  = (ushort_t*)(SMEM + 49152);  // 128x64 bf16 (16KB, phase B)
    float*    yred = (float*)(SMEM + 49152);     // 8192 f32 (32KB, epilogue)
    float*    ssum = (float*)(SMEM + 49152);     // 256 f32 (LN boundary)
    float*    ssq  = ssum + 256;                 // 256 f32

    const int t = threadIdx.x;
    const int l = t & 63;
    const int w = t >> 6;
    const int l4 = (l >> 4) << 2;
    const int drow = l >> 3;
    const int dblk = (l & 7) ^ drow;

    // ---------------- phase A ----------------
    const int wr = w >> 2;      // row half (32 rows)
    const int wc = w & 3;       // col quarter within a 192 half (48 cols)
    f32x4 acc[2][6];
    #pragma unroll
    for (int a = 0; a < 2; ++a)
        #pragma unroll
        for (int b = 0; b < 6; ++b) acc[a][b] = (f32x4)0.f;

    for (int k0 = 0; k0 < DIMX; k0 += 64) {
        dma16(A + (size_t)(m0 + w * 8 + drow) * DIMX + k0 + dblk * 8, As + w * 512);
        #pragma unroll
        for (int h = 0; h < 2; ++h) {
            #pragma unroll
            for (int ii = 0; ii < 3; ++ii) {
                int rloc = w * 24 + ii * 8;
                dma16(B1t + (size_t)(h * 192 + rloc + drow) * DIMX + k0 + dblk * 8,
                      Bs + rloc * 64);
            }
            __syncthreads();
            #pragma unroll
            for (int ks = 0; ks < 2; ++ks) {
                int kq = ks * 4 + (l >> 4);
                short8 af[2], bf3[3];
                #pragma unroll
                for (int fm = 0; fm < 2; ++fm) {
                    int row = wr * 32 + fm * 16 + (l & 15);
                    af[fm] = *(const short8*)&As[row * 64 + ((kq ^ (row & 7)) << 3)];
                }
                #pragma unroll
                for (int cf = 0; cf < 3; ++cf) {
                    int rloc = wc * 48 + cf * 16 + (l & 15);
                    bf3[cf] = *(const short8*)&Bs[rloc * 64 + ((kq ^ (rloc & 7)) << 3)];
                }
                #pragma unroll
                for (int fm = 0; fm < 2; ++fm)
                    #pragma unroll
                    for (int cf = 0; cf < 3; ++cf)
                        acc[fm][h * 3 + cf] = __builtin_amdgcn_mfma_f32_16x16x32_bf16(
                            af[fm], bf3[cf], acc[fm][h * 3 + cf], 0, 0, 0);
            }
            __syncthreads();
        }
    }

    // bias + LN stats (staging region is free after the k-loop's final barrier)
    float bb[6], gg[6], bee[6];
    #pragma unroll
    for (int fc = 0; fc < 6; ++fc) {
        int col = (fc / 3) * 192 + wc * 48 + (fc % 3) * 16 + (l & 15);
        bb[fc] = b1[col]; gg[fc] = g[col]; bee[fc] = be[col];
    }
    #pragma unroll
    for (int fm = 0; fm < 2; ++fm)
        #pragma unroll
        for (int fc = 0; fc < 6; ++fc)
            #pragma unroll
            for (int j = 0; j < 4; ++j) acc[fm][fc][j] += bb[fc];

    #pragma unroll
    for (int fm = 0; fm < 2; ++fm) {
        #pragma unroll
        for (int j = 0; j < 4; ++j) {
            float s = 0.f, q = 0.f;
            #pragma unroll
            for (int fc = 0; fc < 6; ++fc) {
                float v = acc[fm][fc][j];
                s += v; q += v * v;
            }
            #pragma unroll
            for (int o = 1; o < 16; o <<= 1) {
                s += __shfl_xor(s, o);
                q += __shfl_xor(q, o);
            }
            if ((l & 15) == 0) {
                int r = wr * 32 + fm * 16 + l4 + j;
                ssum[r * 4 + wc] = s;
                ssq[r * 4 + wc] = q;
            }
        }
    }
    __syncthreads();

    // LN + mish -> slab
    #pragma unroll
    for (int fm = 0; fm < 2; ++fm) {
        #pragma unroll
        for (int j = 0; j < 4; ++j) {
            int r = wr * 32 + fm * 16 + l4 + j;
            float s = ssum[r * 4 + 0] + ssum[r * 4 + 1] + ssum[r * 4 + 2] + ssum[r * 4 + 3];
            float q = ssq[r * 4 + 0] + ssq[r * 4 + 1] + ssq[r * 4 + 2] + ssq[r * 4 + 3];
            float m = s * (1.f / 384.f);
            float var = q * (1.f / 384.f) - m * m;
            float rs = rsqrtf(var + 1e-5f);
            #pragma unroll
            for (int fc = 0; fc < 6; ++fc) {
                float v = (acc[fm][fc][j] - m) * rs * gg[fc] + bee[fc];
                int c = (fc / 3) * 192 + wc * 48 + (fc % 3) * 16 + (l & 15);
                int panel = c >> 6, cc = c & 63;
                int kb = (cc >> 3) ^ (r & 7);
                slab[panel * 4096 + r * 64 + kb * 8 + (cc & 7)] = f2bf(mishf(v));
            }
        }
    }
    __syncthreads();

    // ---------------- phase B ----------------
    const int wr2 = w >> 2;     // row half (32)
    const int wc2 = w & 3;      // 32-col group within 128-col n-tile
    int kid8[2][4];
    #pragma unroll
    for (int fm = 0; fm < 2; ++fm)
        #pragma unroll
        for (int j = 0; j < 4; ++j)
            kid8[fm][j] = kidx[m0 + wr2 * 32 + fm * 16 + l4 + j];

    for (int nt = 0; nt < 4; ++nt) {
        const int n0t = nt * 128;
        f32x4 acc2[2][2];
        #pragma unroll
        for (int a = 0; a < 2; ++a)
            #pragma unroll
            for (int b = 0; b < 2; ++b) acc2[a][b] = (f32x4)0.f;

        for (int k0 = 0; k0 < MIDV; k0 += 64) {
            #pragma unroll
            for (int ii = 0; ii < 2; ++ii) {
                int nr = w * 16 + ii * 8;
                dma16(B2t + (size_t)(n0t + nr + drow) * MIDV + k0 + dblk * 8,
                      Bs2 + nr * 64);
            }
            __syncthreads();
            const int panel = k0 >> 6;
            #pragma unroll
            for (int ks = 0; ks < 2; ++ks) {
                int kq = ks * 4 + (l >> 4);
                short8 af[2], bf2v[2];
                #pragma unroll
                for (int fm = 0; fm < 2; ++fm) {
                    int row = wr2 * 32 + fm * 16 + (l & 15);
                    af[fm] = *(const short8*)&slab[panel * 4096 + row * 64
                                                   + ((kq ^ (row & 7)) << 3)];
                }
                #pragma unroll
                for (int fn = 0; fn < 2; ++fn) {
                    int nr = wc2 * 32 + fn * 16 + (l & 15);
                    bf2v[fn] = *(const short8*)&Bs2[nr * 64 + ((kq ^ (nr & 7)) << 3)];
                }
                #pragma unroll
                for (int fm = 0; fm < 2; ++fm)
                    #pragma unroll
                    for (int fn = 0; fn < 2; ++fn)
                        acc2[fm][fn] = __builtin_amdgcn_mfma_f32_16x16x32_bf16(
                            af[fm], bf2v[fn], acc2[fm][fn], 0, 0, 0);
            }
            __syncthreads();
        }

        // epilogue: bias + key-multiply -> yred, then segmented scan -> atomics
        #pragma unroll
        for (int fn = 0; fn < 2; ++fn) {
            int cl = wc2 * 32 + fn * 16 + (l & 15);
            float bbv = b2[n0t + cl];
            #pragma unroll
            for (int fm = 0; fm < 2; ++fm) {
                #pragma unroll
                for (int j = 0; j < 4; ++j) {
                    int rl = wr2 * 32 + fm * 16 + l4 + j;
                    float v = (acc2[fm][fn][j] + bbv)
                            * tbl[kid8[fm][j] * HIDN + n0t + cl];
                    yred[cl * 64 + (rl ^ (cl & 31))] = v;
                }
            }
        }
        __syncthreads();
        if (t < 256) {
            int c = t & 127, q = t >> 7;
            int gc = n0t + c;
            float run = 0.f; int curb = -1;
            #pragma unroll
            for (int ch = 0; ch < 2; ++ch) {
                float v16[16]; int b16[16];
                #pragma unroll
                for (int rr = 0; rr < 16; ++rr) {
                    int rl = q * 32 + ch * 16 + rr;
                    v16[rr] = yred[c * 64 + (rl ^ (c & 31))];
                    b16[rr] = batch[m0 + rl];
                }
                #pragma unroll
                for (int rr = 0; rr < 16; ++rr) {
                    if (b16[rr] != curb) {
                        if (curb >= 0) atomicAdd(&zout[curb * HIDN + gc], run);
                        curb = b16[rr]; run = v16[rr];
                    } else run += v16[rr];
                }
            }
            atomicAdd(&zout[curb * HIDN + gc], run);
        }
        __syncthreads();
    }
}

// ---------------- decoder GEMMs (modes 2,3) ----------------
template<int MODE>
__device__ __forceinline__
void mm_body(const ushort_t* __restrict__ A, const ushort_t* __restrict__ Bt,
             const float* __restrict__ bias, void* __restrict__ Cptr, int K,
             const float* __restrict__ tbl, const float* __restrict__ zin,
             const int* __restrict__ rowmap, const int* __restrict__ cntpad)
{
    const int flat = blockIdx.y * gridDim.x + blockIdx.x;
    const int nx = gridDim.x;
    const int xcd = flat & 7;
    const int lin = flat >> 3;
    const int n0 = (lin % nx) * 128;
    const int m0 = ((lin / nx) + ((gridDim.y >> 3) * xcd)) * 128;
    if (m0 >= *cntpad) return;
    __shared__ __align__(16) ushort_t sAB[2 * 128 * 64];
    ushort_t* As = sAB;
    ushort_t* Bs = sAB + 128 * 64;
    const int t = threadIdx.x;
    const int l = t & 63;
    const int w = t >> 6;
    const int wm = (w >> 1) * 64;
    const int wn = (w & 1) * 64;
    const int l4 = (l >> 4) << 2;
    const int drow = l >> 3;
    const int dblk = (l & 7) ^ drow;

    int g4[4], p4[4];
    if (MODE == 2) {
        #pragma unroll
        for (int ii = 0; ii < 4; ++ii) {
            int i = w * 4 + ii;
            int gr = rowmap[m0 + i * 8 + drow];
            if (gr < 0) gr = 0;
            g4[ii] = gr >> 6; p4[ii] = gr & 63;
        }
    }

    f32x4 acc[4][4];
    #pragma unroll
    for (int a = 0; a < 4; ++a)
        #pragma unroll
        for (int b = 0; b < 4; ++b) acc[a][b] = (f32x4)0.f;

    for (int k0 = 0; k0 < K; k0 += 64) {
        if (MODE == 2) {
            #pragma unroll
            for (int ii = 0; ii < 4; ++ii) {
                int i = w * 4 + ii;
                int row = i * 8 + drow;
                const float* zp = zin + g4[ii] * HIDN + k0 + dblk * 8;
                const float* kp = tbl + p4[ii] * HIDN + k0 + dblk * 8;
                float4 z0 = *(const float4*)zp;
                float4 z1 = *(const float4*)(zp + 4);
                float4 q0 = *(const float4*)kp;
                float4 q1 = *(const float4*)(kp + 4);
                ushort4 u0, u1;
                u0.x = f2bf(z0.x * q0.x); u0.y = f2bf(z0.y * q0.y);
                u0.z = f2bf(z0.z * q0.z); u0.w = f2bf(z0.w * q0.w);
                u1.x = f2bf(z1.x * q1.x); u1.y = f2bf(z1.y * q1.y);
                u1.z = f2bf(z1.z * q1.z); u1.w = f2bf(z1.w * q1.w);
                ushort_t* dst = &As[row * 64 + (l & 7) * 8];
                *(ushort4*)dst = u0;
                *(ushort4*)(dst + 4) = u1;
            }
        } else {
            #pragma unroll
            for (int ii = 0; ii < 4; ++ii) {
                int i = w * 4 + ii;
                const ushort_t* gp = A + (size_t)(m0 + i * 8 + drow) * K + k0 + dblk * 8;
                dma16(gp, &As[i * 512]);
            }
        }
        #pragma unroll
        for (int ii = 0; ii < 4; ++ii) {
            int i = w * 4 + ii;
            const ushort_t* gp = Bt + (size_t)(n0 + i * 8 + drow) * K + k0 + dblk * 8;
            dma16(gp, &Bs[i * 512]);
        }
        __syncthreads();
        #pragma unroll
        for (int ks = 0; ks < 2; ++ks) {
            short8 af[4], bfr[4];
            int kq = ks * 4 + (l >> 4);
            #pragma unroll
            for (int fm = 0; fm < 4; ++fm) {
                int row = wm + fm * 16 + (l & 15);
                af[fm] = *(const short8*)&As[row * 64 + ((kq ^ (row & 7)) << 3)];
            }
            #pragma unroll
            for (int fn = 0; fn < 4; ++fn) {
                int row = wn + fn * 16 + (l & 15);
                bfr[fn] = *(const short8*)&Bs[row * 64 + ((kq ^ (row & 7)) << 3)];
            }
            #pragma unroll
            for (int fm = 0; fm < 4; ++fm)
                #pragma unroll
                for (int fn = 0; fn < 4; ++fn)
                    acc[fm][fn] = __builtin_amdgcn_mfma_f32_16x16x32_bf16(
                        af[fm], bfr[fn], acc[fm][fn], 0, 0, 0);
        }
        __syncthreads();
    }

    if (MODE == 2) {
        ushort_t* C = (ushort_t*)Cptr;
        #pragma unroll
        for (int fm = 0; fm < 4; ++fm) {
            int gr0 = m0 + wm + fm * 16 + l4;
            #pragma unroll
            for (int fn = 0; fn < 4; ++fn) {
                int gc = n0 + wn + fn * 16 + (l & 15);
                float bbv = bias[gc];
                #pragma unroll
                for (int j = 0; j < 4; ++j)
                    C[(size_t)(gr0 + j) * MIDD + gc] = f2bf(mishf(acc[fm][fn][j] + bbv));
            }
        }
    } else {
        float* C = (float*)Cptr;
        #pragma unroll
        for (int fm = 0; fm < 4; ++fm) {
            int gr0 = m0 + wm + fm * 16 + l4;
            int om[4];
            #pragma unroll
            for (int j = 0; j < 4; ++j) om[j] = rowmap[gr0 + j];
            #pragma unroll
            for (int fn = 0; fn < 4; ++fn) {
                int gc = n0 + wn + fn * 16 + (l & 15);
                float bbv = bias[gc];
                #pragma unroll
                for (int j = 0; j < 4; ++j)
                    if (om[j] >= 0) C[(size_t)om[j] * DIMX + gc] = acc[fm][fn][j] + bbv;
            }
        }
    }
}

__global__ __launch_bounds__(256, 2)
void k_mm_d1(const ushort_t* Bt, const float* bias, void* C, int K,
             const float* tbl, const float* zin, const int* rowmap, const int* cntpad)
{ mm_body<2>(nullptr, Bt, bias, C, K, tbl, zin, rowmap, cntpad); }

__global__ __launch_bounds__(256, 2)
void k_mm_d2(const ushort_t* A, const ushort_t* Bt, const float* bias, void* C, int K,
             const int* rowmap, const int* cntpad)
{ mm_body<3>(A, Bt, bias, C, K, nullptr, nullptr, rowmap, cntpad); }

// ---------------- launch ----------------
extern "C" void kernel_launch(void* const* d_in, const int* in_sizes, int n_in,
                              void* d_out, int out_size, void* d_ws, size_t ws_size,
                              hipStream_t stream)
{
    const float* x        = (const float*)d_in[0];
    const int*   batch    = (const int*)  d_in[1];
    const float* e_rank_W = (const float*)d_in[3];
    const float* e_rank_b = (const float*)d_in[4];
    const float* e_card_W = (const float*)d_in[5];
    const float* e_card_b = (const float*)d_in[6];
    const float* e_key_W1 = (const float*)d_in[7];
    const float* e_key_b1 = (const float*)d_in[8];
    const float* e_key_g  = (const float*)d_in[9];
    const float* e_key_be = (const float*)d_in[10];
    const float* e_key_W2 = (const float*)d_in[11];
    const float* e_key_b2 = (const float*)d_in[12];
    const float* e_val_W1 = (const float*)d_in[13];
    const float* e_val_b1 = (const float*)d_in[14];
    const float* e_val_g  = (const float*)d_in[15];
    const float* e_val_be = (const float*)d_in[16];
    const float* e_val_W2 = (const float*)d_in[17];
    const float* e_val_b2 = (const float*)d_in[18];
    const float* d_key_W1 = (const float*)d_in[19];
    const float* d_key_b1 = (const float*)d_in[20];
    const float* d_key_g  = (const float*)d_in[21];
    const float* d_key_be = (const float*)d_in[22];
    const float* d_key_W2 = (const float*)d_in[23];
    const float* d_key_b2 = (const float*)d_in[24];
    const float* d_dec_W1 = (const float*)d_in[25];
    const float* d_dec_b1 = (const float*)d_in[26];
    const float* d_dec_W2 = (const float*)d_in[27];
    const float* d_dec_b2 = (const float*)d_in[28];
    const float* d_size_W1= (const float*)d_in[29];
    const float* d_size_b1= (const float*)d_in[30];
    const float* d_size_g = (const float*)d_in[31];
    const float* d_size_be= (const float*)d_in[32];
    const float* d_size_W2= (const float*)d_in[33];
    const float* d_size_b2= (const float*)d_in[34];

    char* ws = (char*)d_ws;
    unsigned int* maxmag  = (unsigned int*)(ws + 8448);
    int*          kidx    = (int*)         (ws + 8704);
    float*        mag     = (float*)       (ws + 270848);
    float*        enc_tbl = (float*)       (ws + 532992);
    float*        dec_tbl = (float*)       (ws + 666112);
    float*        z       = (float*)       (ws + 797184);
    int*          ndec    = (int*)         (ws + 4991488);
    int*          cntpad  = (int*)         (ws + 4999684);
    int*          rowmap  = (int*)         (ws + 5000192);
    ushort_t*     evW1t   = (ushort_t*)    (ws + 5524480);
    ushort_t*     evW2t   = (ushort_t*)    (ws + 5721088);
    ushort_t*     ddW1t   = (ushort_t*)    (ws + 6114304);
    ushort_t*     ddW2t   = (ushort_t*)    (ws + 6507520);
    ushort_t*     xb      = (ushort_t*)    (ws + 6704384);              // 32 MB
    ushort_t*     Hd      = (ushort_t*)    (ws + 6704384 + 33554432);   // 96 MB

    float* out_x = (float*)d_out;
    float* out_b = out_x + (size_t)NB * MAXNN * DIMX;
    float* out_m = out_b + NB * MAXNN;

    k_setup<<<dim3(129 + NB + 1152), dim3(512), 0, stream>>>(
        e_key_W1, e_key_b1, e_key_g, e_key_be, e_key_W2, e_key_b2,
        d_key_W1, d_key_b1, d_key_g, d_key_be, d_key_W2, d_key_b2,
        enc_tbl, dec_tbl, batch, e_card_W, e_card_b, z,
        e_val_W1, evW1t, e_val_W2, evW2t, d_dec_W1, ddW1t, d_dec_W2, ddW2t,
        maxmag);
    k_mag<<<dim3(4096), dim3(256), 0, stream>>>(x, e_rank_W, e_rank_b, mag, maxmag, xb);
    k_rank<<<dim3(256), dim3(256), 0, stream>>>(batch, mag, maxmag, kidx);

    k_enc<<<dim3(1024), dim3(512), 0, stream>>>(xb, evW1t, e_val_b1, e_val_g, e_val_be,
                                                evW2t, e_val_b2, enc_tbl, kidx, batch, z);

    k_size<<<dim3(NB / 4), dim3(256), 0, stream>>>(z, d_size_W1, d_size_b1, d_size_g,
                                                   d_size_be, d_size_W2, d_size_b2, ndec);
    k_post<<<dim3(1024), dim3(256), 0, stream>>>(ndec, out_x, out_b, out_m,
                                                 rowmap, cntpad);
    k_mm_d1<<<dim3(3, 1024), dim3(256), 0, stream>>>(ddW1t, d_dec_b1, Hd, HIDN,
                                                     dec_tbl, z, rowmap, cntpad);
    k_mm_d2<<<dim3(2, 1024), dim3(256), 0, stream>>>(Hd, ddW2t, d_dec_b2, out_x, MIDD,
                                                     rowmap, cntpad);
}

// Round 9
// 484.572 us; speedup vs baseline: 1.0496x; 1.0496x over previous
//
#include <hip/hip_runtime.h>

#define NPTS   65536
#define NB     2048
#define DIMX   256
#define HIDN   512
#define MAXNN  64
#define MIDK   288
#define MIDV   384
#define MIDD   384
#define MIDS   256

typedef unsigned short ushort_t;
typedef __attribute__((ext_vector_type(8))) short short8;
typedef __attribute__((ext_vector_type(4))) float f32x4;

// ---------------- helpers ----------------
// mish(x) = x*tanh(softplus(x)) = x * e(e+2)/(e(e+2)+2), e = exp(x)  [exact identity]
__device__ __forceinline__ float mishf(float x) {
    float e = __expf(fminf(x, 30.f));
    float n = e * (e + 2.f);
    return x * n * __builtin_amdgcn_rcpf(n + 2.f);
}
__device__ __forceinline__ ushort_t f2bf(float f) {
    unsigned u = __float_as_uint(f);
    u += 0x7fffu + ((u >> 16) & 1u);
    return (ushort_t)(u >> 16);
}
__device__ __forceinline__ float bf2f(ushort_t h) {
    return __uint_as_float(((unsigned)h) << 16);
}
__device__ __forceinline__ void dma16(const void* g, void* lds) {
    __builtin_amdgcn_global_load_lds(
        (const __attribute__((address_space(1))) unsigned int*)g,
        (__attribute__((address_space(3))) unsigned int*)lds, 16, 0, 0);
}
__device__ __forceinline__ int lbound(const int* __restrict__ a, int lo, int hi, int v) {
    while (lo < hi) { int m = (lo + hi) >> 1; if (a[m] < v) lo = m + 1; else hi = m; }
    return lo;
}

// ---------------- small kernels ----------------
__global__ __launch_bounds__(256)
void k_mag(const float* __restrict__ x, const float* __restrict__ rW,
           const float* __restrict__ rb, float* __restrict__ mag,
           unsigned int* __restrict__ maxmag, ushort_t* __restrict__ xb)
{
    const int lane = threadIdx.x & 63;
    const int wave = threadIdx.x >> 6;
    const int gw = blockIdx.x * 4 + wave;   // 16384 waves
    float4 wv = *(const float4*)(rW + lane * 4);
    float bias = rb[0];
    float lmax = 0.f;
    for (int pt = gw; pt < NPTS; pt += 16384) {
        float4 xv = *(const float4*)(x + (size_t)pt * DIMX + lane * 4);
        ushort4 u;
        u.x = f2bf(xv.x); u.y = f2bf(xv.y); u.z = f2bf(xv.z); u.w = f2bf(xv.w);
        *(ushort4*)(xb + (size_t)pt * DIMX + lane * 4) = u;
        double d = (double)xv.x * wv.x + (double)xv.y * wv.y
                 + (double)xv.z * wv.z + (double)xv.w * wv.w;
        #pragma unroll
        for (int o = 32; o > 0; o >>= 1) d += __shfl_xor(d, o);
        float s = fabsf((float)(d + (double)bias));
        if (lane == 0) mag[pt] = s;
        lmax = fmaxf(lmax, s);
    }
    __shared__ float wm[4];
    if (lane == 0) wm[wave] = lmax;
    __syncthreads();
    if (threadIdx.x == 0) {
        float m = fmaxf(fmaxf(wm[0], wm[1]), fmaxf(wm[2], wm[3]));
        atomicMax(maxmag, __float_as_uint(m));
    }
}

__global__ __launch_bounds__(256)
void k_rank(const int* __restrict__ batch, const float* __restrict__ mag,
            const unsigned int* __restrict__ maxmag, int* __restrict__ kidx)
{
    int i = blockIdx.x * 256 + threadIdx.x;
    if (i >= NPTS) return;
    int b = batch[i];
    int s = lbound(batch, 0, NPTS, b);
    int e = lbound(batch, s, NPTS, b + 1);
    float M = __uint_as_float(*maxmag);
    float kb = __fmul_rn((float)b, M);
    float ki = __fadd_rn(kb, mag[i]);
    int r = 0;
    for (int j = s; j < e; ++j) {
        float kj = __fadd_rn(kb, mag[j]);
        r += (kj < ki) || (kj == ki && j < i);
    }
    kidx[i] = (r < MAXNN) ? r : MAXNN;
}

// merged setup: blocks 0..128 key tables; 129..2176 card-init of z; rest wt; blk0 inits maxmag
__global__ __launch_bounds__(512)
void k_setup(const float* __restrict__ eW1, const float* __restrict__ eb1,
             const float* __restrict__ eg, const float* __restrict__ ebe,
             const float* __restrict__ eW2, const float* __restrict__ eb2,
             const float* __restrict__ dW1, const float* __restrict__ db1,
             const float* __restrict__ dg, const float* __restrict__ dbe,
             const float* __restrict__ dW2, const float* __restrict__ db2,
             float* __restrict__ enc_tbl, float* __restrict__ dec_tbl,
             const int* __restrict__ batch, const float* __restrict__ cardW,
             const float* __restrict__ cardb, float* __restrict__ z,
             const float* __restrict__ V0, ushort_t* __restrict__ T0,
             const float* __restrict__ V1, ushort_t* __restrict__ T1,
             const float* __restrict__ V2, ushort_t* __restrict__ T2,
             const float* __restrict__ V3, ushort_t* __restrict__ T3,
             unsigned int* __restrict__ maxmag)
{
    const int blk = blockIdx.x;
    const int t = threadIdx.x;
    if (blk == 0 && t == 0) *maxmag = 0u;
    if (blk < 129) {
        const float *W1, *b1, *g, *be, *W2, *b2; float* out; int wrow;
        if (blk < 65) {
            W1 = eW1; b1 = eb1; g = eg; be = ebe; W2 = eW2; b2 = eb2;
            out = enc_tbl + blk * HIDN; wrow = (blk < 64) ? blk : -1;
        } else {
            int r = blk - 65;
            W1 = dW1; b1 = db1; g = dg; be = dbe; W2 = dW2; b2 = db2;
            out = dec_tbl + r * HIDN; wrow = r;
        }
        __shared__ float h[MIDK];
        __shared__ float red[512];
        float v = 0.f;
        if (t < MIDK) v = b1[t] + (wrow >= 0 ? W1[wrow * MIDK + t] : 0.f);
        red[t] = (t < MIDK) ? v : 0.f;
        __syncthreads();
        for (int o = 256; o > 0; o >>= 1) { if (t < o) red[t] += red[t + o]; __syncthreads(); }
        float m = red[0] / (float)MIDK;
        __syncthreads();
        float d = v - m;
        red[t] = (t < MIDK) ? d * d : 0.f;
        __syncthreads();
        for (int o = 256; o > 0; o >>= 1) { if (t < o) red[t] += red[t + o]; __syncthreads(); }
        float rs = rsqrtf(red[0] / (float)MIDK + 1e-5f);
        __syncthreads();
        if (t < MIDK) h[t] = mishf(d * rs * g[t] + be[t]);
        __syncthreads();
        float acc = b2[t];
        #pragma unroll 8
        for (int k = 0; k < MIDK; ++k) acc = fmaf(h[k], W2[k * HIDN + t], acc);
        out[t] = acc;
    } else if (blk < 129 + NB) {
        int b = blk - 129;
        int s = lbound(batch, 0, NPTS, b);
        int e = lbound(batch, s, NPTS, b + 1);
        float n = (float)(e - s);
        z[b * HIDN + t] = fmaf(n, cardW[t], cardb[t]);
    } else {
        int idx = (blk - (129 + NB)) * 512 + t;
        const float* W; ushort_t* T; int N, K, off;
        if (idx < 98304)       { W = V0; T = T0; K = 256; N = 384; off = idx; }
        else if (idx < 294912) { W = V1; T = T1; K = 384; N = 512; off = idx - 98304; }
        else if (idx < 491520) { W = V2; T = T2; K = 512; N = 384; off = idx - 294912; }
        else                   { W = V3; T = T3; K = 384; N = 256; off = idx - 491520; }
        int k = off / N, n = off - k * N;
        T[(size_t)n * K + k] = f2bf(W[off]);
    }
}

// d_size MLP: 4 batches per block (4x W1 reuse)
__global__ __launch_bounds__(256)
void k_size(const float* __restrict__ z, const float* __restrict__ W1,
            const float* __restrict__ b1, const float* __restrict__ g,
            const float* __restrict__ be, const float* __restrict__ W2,
            const float* __restrict__ b2, int* __restrict__ ndec)
{
    const int b0 = blockIdx.x * 4, t = threadIdx.x;
    __shared__ float zr[4][HIDN];
    __shared__ float red[4][256];
    #pragma unroll
    for (int gI = 0; gI < 4; ++gI) {
        zr[gI][t] = z[(b0 + gI) * HIDN + t];
        zr[gI][t + 256] = z[(b0 + gI) * HIDN + 256 + t];
    }
    __syncthreads();
    float acc[4];
    float bb1 = b1[t];
    #pragma unroll
    for (int gI = 0; gI < 4; ++gI) acc[gI] = bb1;
    #pragma unroll 8
    for (int k = 0; k < HIDN; ++k) {
        float wv = W1[k * MIDS + t];
        #pragma unroll
        for (int gI = 0; gI < 4; ++gI) acc[gI] = fmaf(zr[gI][k], wv, acc[gI]);
    }
    #pragma unroll
    for (int gI = 0; gI < 4; ++gI) red[gI][t] = acc[gI];
    __syncthreads();
    for (int o = 128; o > 0; o >>= 1) {
        if (t < o) {
            #pragma unroll
            for (int gI = 0; gI < 4; ++gI) red[gI][t] += red[gI][t + o];
        }
        __syncthreads();
    }
    float mm[4];
    #pragma unroll
    for (int gI = 0; gI < 4; ++gI) mm[gI] = red[gI][0] * (1.f / 256.f);
    __syncthreads();
    #pragma unroll
    for (int gI = 0; gI < 4; ++gI) { float d = acc[gI] - mm[gI]; red[gI][t] = d * d; }
    __syncthreads();
    for (int o = 128; o > 0; o >>= 1) {
        if (t < o) {
            #pragma unroll
            for (int gI = 0; gI < 4; ++gI) red[gI][t] += red[gI][t + o];
        }
        __syncthreads();
    }
    float rs[4];
    #pragma unroll
    for (int gI = 0; gI < 4; ++gI) rs[gI] = rsqrtf(red[gI][0] * (1.f / 256.f) + 1e-5f);
    __syncthreads();
    float w2 = W2[t], gg = g[t], bbe = be[t];
    #pragma unroll
    for (int gI = 0; gI < 4; ++gI) {
        float h = mishf((acc[gI] - mm[gI]) * rs[gI] * gg + bbe);
        red[gI][t] = h * w2;
    }
    __syncthreads();
    for (int o = 128; o > 0; o >>= 1) {
        if (t < o) {
            #pragma unroll
            for (int gI = 0; gI < 4; ++gI) red[gI][t] += red[gI][t + o];
        }
        __syncthreads();
    }
    if (t < 4) {
        float logit = red[t][0] + b2[0];
        float n = rintf(logit);
        n = fminf(fmaxf(n, 0.f), 64.f);
        ndec[b0 + t] = (int)n;
    }
}

// zero out_x + write batch_out/mask + (block 0) compact+pad. grid 1024x256.
__global__ __launch_bounds__(256)
void k_post(const int* __restrict__ ndec, float* __restrict__ out_x,
            float* __restrict__ outb, float* __restrict__ outm,
            int* __restrict__ rowmap, int* __restrict__ cntpad)
{
    const int gidx = blockIdx.x * 256 + threadIdx.x;
    float4 z4 = make_float4(0.f, 0.f, 0.f, 0.f);
    float4* p = (float4*)out_x;
    #pragma unroll
    for (int i = 0; i < 32; ++i) p[gidx + i * 262144] = z4;
    if (gidx < NB * MAXNN) {
        outb[gidx] = (float)(gidx >> 6);
        outm[gidx] = ((gidx & 63) < ndec[gidx >> 6]) ? 1.f : 0.f;
    }
    if (blockIdx.x == 0) {
        __shared__ int lcnt;
        if (threadIdx.x == 0) lcnt = 0;
        __syncthreads();
        for (int b = threadIdx.x; b < NB; b += 256) {
            int n = ndec[b];
            if (n > 0) {
                int base = atomicAdd(&lcnt, n);
                for (int q = 0; q < n; ++q) rowmap[base + q] = b * 64 + q;
            }
        }
        __syncthreads();
        int c = lcnt;
        int pad = (c + 127) & ~127;
        for (int i = c + threadIdx.x; i < pad; i += 256) rowmap[i] = -1;
        if (threadIdx.x == 0) *cntpad = pad;
    }
}

// ---------------- E1 fused: Hb = bf16(mish(LN(xb @ W1t + b1))) ----------------
// 512 threads, 8 waves in 2(row)x4(col) layout; block computes full 128x384 slab.
__global__ __launch_bounds__(512, 2)
void k_mm_e1f(const ushort_t* __restrict__ A, const ushort_t* __restrict__ Bt,
              const float* __restrict__ bias, const float* __restrict__ g,
              const float* __restrict__ be, ushort_t* __restrict__ C)
{
    const int m0 = blockIdx.x * 128;
    __shared__ __align__(16) ushort_t As[128 * 64];    // 16 KB
    __shared__ __align__(16) ushort_t Bs[384 * 64];    // 48 KB
    const int t = threadIdx.x;
    const int l = t & 63;
    const int w = t >> 6;
    const int wm = (w >> 2) * 64;
    const int wq = (w & 3) * 96;
    const int l4 = (l >> 4) << 2;
    const int drow = l >> 3;
    const int dblk = (l & 7) ^ drow;

    f32x4 acc[4][6];
    #pragma unroll
    for (int a = 0; a < 4; ++a)
        #pragma unroll
        for (int b = 0; b < 6; ++b) acc[a][b] = (f32x4)0.f;

    for (int k0 = 0; k0 < DIMX; k0 += 64) {
        #pragma unroll
        for (int ii = 0; ii < 2; ++ii) {
            int i = w * 2 + ii;
            dma16(A + (size_t)(m0 + i * 8 + drow) * DIMX + k0 + dblk * 8, &As[i * 512]);
        }
        #pragma unroll
        for (int ii = 0; ii < 6; ++ii) {
            int i = w * 6 + ii;
            dma16(Bt + (size_t)(i * 8 + drow) * DIMX + k0 + dblk * 8, &Bs[i * 512]);
        }
        __syncthreads();
        #pragma unroll
        for (int ks = 0; ks < 2; ++ks) {
            int kq = ks * 4 + (l >> 4);
            short8 af[4], bfr[6];
            #pragma unroll
            for (int fm = 0; fm < 4; ++fm) {
                int row = wm + fm * 16 + (l & 15);
                af[fm] = *(const short8*)&As[row * 64 + ((kq ^ (row & 7)) << 3)];
            }
            #pragma unroll
            for (int fn = 0; fn < 6; ++fn) {
                int row = wq + fn * 16 + (l & 15);
                bfr[fn] = *(const short8*)&Bs[row * 64 + ((kq ^ (row & 7)) << 3)];
            }
            #pragma unroll
            for (int fm = 0; fm < 4; ++fm)
                #pragma unroll
                for (int fn = 0; fn < 6; ++fn)
                    acc[fm][fn] = __builtin_amdgcn_mfma_f32_16x16x32_bf16(
                        af[fm], bfr[fn], acc[fm][fn], 0, 0, 0);
        }
        __syncthreads();
    }

    float bb[6], gg[6], bee[6];
    #pragma unroll
    for (int fn = 0; fn < 6; ++fn) {
        int col = wq + fn * 16 + (l & 15);
        bb[fn] = bias[col]; gg[fn] = g[col]; bee[fn] = be[col];
    }
    #pragma unroll
    for (int fm = 0; fm < 4; ++fm)
        #pragma unroll
        for (int fn = 0; fn < 6; ++fn)
            #pragma unroll
            for (int j = 0; j < 4; ++j) acc[fm][fn][j] += bb[fn];

    float* ssum = (float*)As;
    float* ssq  = ssum + 512;
    #pragma unroll
    for (int fm = 0; fm < 4; ++fm) {
        #pragma unroll
        for (int j = 0; j < 4; ++j) {
            float s = 0.f, q = 0.f;
            #pragma unroll
            for (int fn = 0; fn < 6; ++fn) {
                float v = acc[fm][fn][j];
                s += v; q += v * v;
            }
            #pragma unroll
            for (int o = 1; o < 16; o <<= 1) {
                s += __shfl_xor(s, o);
                q += __shfl_xor(q, o);
            }
            if ((l & 15) == 0) {
                int r = wm + fm * 16 + l4 + j;
                ssum[r * 4 + (w & 3)] = s;
                ssq[r * 4 + (w & 3)] = q;
            }
        }
    }
    __syncthreads();
    #pragma unroll
    for (int fm = 0; fm < 4; ++fm) {
        #pragma unroll
        for (int j = 0; j < 4; ++j) {
            int r = wm + fm * 16 + l4 + j;
            float s = ssum[r * 4 + 0] + ssum[r * 4 + 1] + ssum[r * 4 + 2] + ssum[r * 4 + 3];
            float q = ssq[r * 4 + 0] + ssq[r * 4 + 1] + ssq[r * 4 + 2] + ssq[r * 4 + 3];
            float m = s * (1.f / 384.f);
            float var = q * (1.f / 384.f) - m * m;
            float rs = rsqrtf(var + 1e-5f);
            #pragma unroll
            for (int fn = 0; fn < 6; ++fn) {
                float v = (acc[fm][fn][j] - m) * rs * gg[fn] + bee[fn];
                C[(size_t)(m0 + r) * MIDV + wq + fn * 16 + (l & 15)] = f2bf(mishf(v));
            }
        }
    }
}

// ---------------- E2: (Hb @ W2t + b2) * enc_tbl[kidx]; segmented scan -> atomicAdd z ----
__global__ __launch_bounds__(256, 2)
void k_mm_e2(const ushort_t* __restrict__ A, const ushort_t* __restrict__ Bt,
             const float* __restrict__ bias, int K, const float* __restrict__ tbl,
             const int* __restrict__ kidx, const int* __restrict__ batch,
             float* __restrict__ zout)
{
    const int flat = blockIdx.y * gridDim.x + blockIdx.x;
    const int nx = gridDim.x;
    const int xcd = flat & 7;
    const int lin = flat >> 3;
    const int n0 = (lin % nx) * 128;
    const int m0 = ((lin / nx) + ((gridDim.y >> 3) * xcd)) * 128;
    __shared__ __align__(16) ushort_t sAB[2 * 128 * 64];
    __shared__ int barr[128];
    __shared__ int karr[128];
    ushort_t* As = sAB;
    ushort_t* Bs = sAB + 128 * 64;
    const int t = threadIdx.x;
    const int l = t & 63;
    const int w = t >> 6;
    const int wm = (w >> 1) * 64;
    const int wn = (w & 1) * 64;
    const int l4 = (l >> 4) << 2;
    const int drow = l >> 3;
    const int dblk = (l & 7) ^ drow;

    if (t < 128) { barr[t] = batch[m0 + t]; karr[t] = kidx[m0 + t]; }

    f32x4 acc[4][4];
    #pragma unroll
    for (int a = 0; a < 4; ++a)
        #pragma unroll
        for (int b = 0; b < 4; ++b) acc[a][b] = (f32x4)0.f;

    for (int k0 = 0; k0 < K; k0 += 64) {
        #pragma unroll
        for (int ii = 0; ii < 4; ++ii) {
            int i = w * 4 + ii;
            dma16(A + (size_t)(m0 + i * 8 + drow) * K + k0 + dblk * 8, &As[i * 512]);
        }
        #pragma unroll
        for (int ii = 0; ii < 4; ++ii) {
            int i = w * 4 + ii;
            dma16(Bt + (size_t)(n0 + i * 8 + drow) * K + k0 + dblk * 8, &Bs[i * 512]);
        }
        __syncthreads();
        #pragma unroll
        for (int ks = 0; ks < 2; ++ks) {
            short8 af[4], bfr[4];
            int kq = ks * 4 + (l >> 4);
            #pragma unroll
            for (int fm = 0; fm < 4; ++fm) {
                int row = wm + fm * 16 + (l & 15);
                af[fm] = *(const short8*)&As[row * 64 + ((kq ^ (row & 7)) << 3)];
            }
            #pragma unroll
            for (int fn = 0; fn < 4; ++fn) {
                int row = wn + fn * 16 + (l & 15);
                bfr[fn] = *(const short8*)&Bs[row * 64 + ((kq ^ (row & 7)) << 3)];
            }
            #pragma unroll
            for (int fm = 0; fm < 4; ++fm)
                #pragma unroll
                for (int fn = 0; fn < 4; ++fn)
                    acc[fm][fn] = __builtin_amdgcn_mfma_f32_16x16x32_bf16(
                        af[fm], bfr[fn], acc[fm][fn], 0, 0, 0);
        }
        __syncthreads();
    }

    // epilogue: bias + key multiply -> yred, register-preloaded segmented scan -> atomics
    float* yred = (float*)sAB;     // 128 cols x 64 rows
    #pragma unroll
    for (int pass = 0; pass < 2; ++pass) {
        if ((w >> 1) == pass) {
            #pragma unroll
            for (int fn = 0; fn < 4; ++fn) {
                int cl = wn + fn * 16 + (l & 15);
                float bbv = bias[n0 + cl];
                #pragma unroll
                for (int fm = 0; fm < 4; ++fm) {
                    #pragma unroll
                    for (int j = 0; j < 4; ++j) {
                        int rl = fm * 16 + l4 + j;
                        float v = (acc[fm][fn][j] + bbv)
                                * tbl[karr[pass * 64 + rl] * HIDN + (n0 + cl)];
                        yred[cl * 64 + (rl ^ (cl & 31))] = v;
                    }
                }
            }
        }
        __syncthreads();
        {
            int c = t & 127, q = t >> 7;
            int gc = n0 + c;
            float run = 0.f; int curb = -1;
            #pragma unroll
            for (int ch = 0; ch < 2; ++ch) {
                float v16[16]; int b16[16];
                #pragma unroll
                for (int rr = 0; rr < 16; ++rr) {
                    int rl = q * 32 + ch * 16 + rr;
                    v16[rr] = yred[c * 64 + (rl ^ (c & 31))];
                    b16[rr] = barr[pass * 64 + rl];
                }
                #pragma unroll
                for (int rr = 0; rr < 16; ++rr) {
                    if (b16[rr] != curb) {
                        if (curb >= 0) atomicAdd(&zout[curb * HIDN + gc], run);
                        curb = b16[rr]; run = v16[rr];
                    } else run += v16[rr];
                }
            }
            atomicAdd(&zout[curb * HIDN + gc], run);
        }
        __syncthreads();
    }
}

// ---------------- decoder GEMMs (modes 2,3) ----------------
template<int MODE>
__device__ __forceinline__
void mm_body(const ushort_t* __restrict__ A, const ushort_t* __restrict__ Bt,
             const float* __restrict__ bias, void* __restrict__ Cptr, int K,
             const float* __restrict__ tbl, const float* __restrict__ zin,
             const int* __restrict__ rowmap, const int* __restrict__ cntpad)
{
    const int flat = blockIdx.y * gridDim.x + blockIdx.x;
    const int nx = gridDim.x;
    const int xcd = flat & 7;
    const int lin = flat >> 3;
    const int n0 = (lin % nx) * 128;
    const int m0 = ((lin / nx) + ((gridDim.y >> 3) * xcd)) * 128;
    if (m0 >= *cntpad) return;
    __shared__ __align__(16) ushort_t sAB[2 * 128 * 64];
    ushort_t* As = sAB;
    ushort_t* Bs = sAB + 128 * 64;
    const int t = threadIdx.x;
    const int l = t & 63;
    const int w = t >> 6;
    const int wm = (w >> 1) * 64;
    const int wn = (w & 1) * 64;
    const int l4 = (l >> 4) << 2;
    const int drow = l >> 3;
    const int dblk = (l & 7) ^ drow;

    int g4[4], p4[4];
    if (MODE == 2) {
        #pragma unroll
        for (int ii = 0; ii < 4; ++ii) {
            int i = w * 4 + ii;
            int gr = rowmap[m0 + i * 8 + drow];
            if (gr < 0) gr = 0;
            g4[ii] = gr >> 6; p4[ii] = gr & 63;
        }
    }

    f32x4 acc[4][4];
    #pragma unroll
    for (int a = 0; a < 4; ++a)
        #pragma unroll
        for (int b = 0; b < 4; ++b) acc[a][b] = (f32x4)0.f;

    for (int k0 = 0; k0 < K; k0 += 64) {
        if (MODE == 2) {
            #pragma unroll
            for (int ii = 0; ii < 4; ++ii) {
                int i = w * 4 + ii;
                int row = i * 8 + drow;
                const float* zp = zin + g4[ii] * HIDN + k0 + dblk * 8;
                const float* kp = tbl + p4[ii] * HIDN + k0 + dblk * 8;
                float4 z0 = *(const float4*)zp;
                float4 z1 = *(const float4*)(zp + 4);
                float4 q0 = *(const float4*)kp;
                float4 q1 = *(const float4*)(kp + 4);
                ushort4 u0, u1;
                u0.x = f2bf(z0.x * q0.x); u0.y = f2bf(z0.y * q0.y);
                u0.z = f2bf(z0.z * q0.z); u0.w = f2bf(z0.w * q0.w);
                u1.x = f2bf(z1.x * q1.x); u1.y = f2bf(z1.y * q1.y);
                u1.z = f2bf(z1.z * q1.z); u1.w = f2bf(z1.w * q1.w);
                ushort_t* dst = &As[row * 64 + (l & 7) * 8];
                *(ushort4*)dst = u0;
                *(ushort4*)(dst + 4) = u1;
            }
        } else {
            #pragma unroll
            for (int ii = 0; ii < 4; ++ii) {
                int i = w * 4 + ii;
                const ushort_t* gp = A + (size_t)(m0 + i * 8 + drow) * K + k0 + dblk * 8;
                dma16(gp, &As[i * 512]);
            }
        }
        #pragma unroll
        for (int ii = 0; ii < 4; ++ii) {
            int i = w * 4 + ii;
            const ushort_t* gp = Bt + (size_t)(n0 + i * 8 + drow) * K + k0 + dblk * 8;
            dma16(gp, &Bs[i * 512]);
        }
        __syncthreads();
        #pragma unroll
        for (int ks = 0; ks < 2; ++ks) {
            short8 af[4], bfr[4];
            int kq = ks * 4 + (l >> 4);
            #pragma unroll
            for (int fm = 0; fm < 4; ++fm) {
                int row = wm + fm * 16 + (l & 15);
                af[fm] = *(const short8*)&As[row * 64 + ((kq ^ (row & 7)) << 3)];
            }
            #pragma unroll
            for (int fn = 0; fn < 4; ++fn) {
                int row = wn + fn * 16 + (l & 15);
                bfr[fn] = *(const short8*)&Bs[row * 64 + ((kq ^ (row & 7)) << 3)];
            }
            #pragma unroll
            for (int fm = 0; fm < 4; ++fm)
                #pragma unroll
                for (int fn = 0; fn < 4; ++fn)
                    acc[fm][fn] = __builtin_amdgcn_mfma_f32_16x16x32_bf16(
                        af[fm], bfr[fn], acc[fm][fn], 0, 0, 0);
        }
        __syncthreads();
    }

    if (MODE == 2) {
        ushort_t* C = (ushort_t*)Cptr;
        #pragma unroll
        for (int fm = 0; fm < 4; ++fm) {
            int gr0 = m0 + wm + fm * 16 + l4;
            #pragma unroll
            for (int fn = 0; fn < 4; ++fn) {
                int gc = n0 + wn + fn * 16 + (l & 15);
                float bbv = bias[gc];
                #pragma unroll
                for (int j = 0; j < 4; ++j)
                    C[(size_t)(gr0 + j) * MIDD + gc] = f2bf(mishf(acc[fm][fn][j] + bbv));
            }
        }
    } else {
        float* C = (float*)Cptr;
        #pragma unroll
        for (int fm = 0; fm < 4; ++fm) {
            int gr0 = m0 + wm + fm * 16 + l4;
            int om[4];
            #pragma unroll
            for (int j = 0; j < 4; ++j) om[j] = rowmap[gr0 + j];
            #pragma unroll
            for (int fn = 0; fn < 4; ++fn) {
                int gc = n0 + wn + fn * 16 + (l & 15);
                float bbv = bias[gc];
                #pragma unroll
                for (int j = 0; j < 4; ++j)
                    if (om[j] >= 0) C[(size_t)om[j] * DIMX + gc] = acc[fm][fn][j] + bbv;
            }
        }
    }
}

__global__ __launch_bounds__(256, 2)
void k_mm_d1(const ushort_t* Bt, const float* bias, void* C, int K,
             const float* tbl, const float* zin, const int* rowmap, const int* cntpad)
{ mm_body<2>(nullptr, Bt, bias, C, K, tbl, zin, rowmap, cntpad); }

__global__ __launch_bounds__(256, 2)
void k_mm_d2(const ushort_t* A, const ushort_t* Bt, const float* bias, void* C, int K,
             const int* rowmap, const int* cntpad)
{ mm_body<3>(A, Bt, bias, C, K, nullptr, nullptr, rowmap, cntpad); }

// ---------------- launch ----------------
extern "C" void kernel_launch(void* const* d_in, const int* in_sizes, int n_in,
                              void* d_out, int out_size, void* d_ws, size_t ws_size,
                              hipStream_t stream)
{
    const float* x        = (const float*)d_in[0];
    const int*   batch    = (const int*)  d_in[1];
    const float* e_rank_W = (const float*)d_in[3];
    const float* e_rank_b = (const float*)d_in[4];
    const float* e_card_W = (const float*)d_in[5];
    const float* e_card_b = (const float*)d_in[6];
    const float* e_key_W1 = (const float*)d_in[7];
    const float* e_key_b1 = (const float*)d_in[8];
    const float* e_key_g  = (const float*)d_in[9];
    const float* e_key_be = (const float*)d_in[10];
    const float* e_key_W2 = (const float*)d_in[11];
    const float* e_key_b2 = (const float*)d_in[12];
    const float* e_val_W1 = (const float*)d_in[13];
    const float* e_val_b1 = (const float*)d_in[14];
    const float* e_val_g  = (const float*)d_in[15];
    const float* e_val_be = (const float*)d_in[16];
    const float* e_val_W2 = (const float*)d_in[17];
    const float* e_val_b2 = (const float*)d_in[18];
    const float* d_key_W1 = (const float*)d_in[19];
    const float* d_key_b1 = (const float*)d_in[20];
    const float* d_key_g  = (const float*)d_in[21];
    const float* d_key_be = (const float*)d_in[22];
    const float* d_key_W2 = (const float*)d_in[23];
    const float* d_key_b2 = (const float*)d_in[24];
    const float* d_dec_W1 = (const float*)d_in[25];
    const float* d_dec_b1 = (const float*)d_in[26];
    const float* d_dec_W2 = (const float*)d_in[27];
    const float* d_dec_b2 = (const float*)d_in[28];
    const float* d_size_W1= (const float*)d_in[29];
    const float* d_size_b1= (const float*)d_in[30];
    const float* d_size_g = (const float*)d_in[31];
    const float* d_size_be= (const float*)d_in[32];
    const float* d_size_W2= (const float*)d_in[33];
    const float* d_size_b2= (const float*)d_in[34];

    char* ws = (char*)d_ws;
    unsigned int* maxmag  = (unsigned int*)(ws + 8448);
    int*          kidx    = (int*)         (ws + 8704);
    float*        mag     = (float*)       (ws + 270848);
    float*        enc_tbl = (float*)       (ws + 532992);
    float*        dec_tbl = (float*)       (ws + 666112);
    float*        z       = (float*)       (ws + 797184);
    int*          ndec    = (int*)         (ws + 4991488);
    int*          cntpad  = (int*)         (ws + 4999684);
    int*          rowmap  = (int*)         (ws + 5000192);
    ushort_t*     evW1t   = (ushort_t*)    (ws + 5524480);
    ushort_t*     evW2t   = (ushort_t*)    (ws + 5721088);
    ushort_t*     ddW1t   = (ushort_t*)    (ws + 6114304);
    ushort_t*     ddW2t   = (ushort_t*)    (ws + 6507520);
    ushort_t*     xb      = (ushort_t*)    (ws + 6704384);              // 32 MB
    ushort_t*     Hb      = (ushort_t*)    (ws + 6704384 + 33554432);   // 48 MB (aliases Hd)
    ushort_t*     Hd      = (ushort_t*)    (ws + 6704384 + 33554432);   // 96 MB

    float* out_x = (float*)d_out;
    float* out_b = out_x + (size_t)NB * MAXNN * DIMX;
    float* out_m = out_b + NB * MAXNN;

    k_setup<<<dim3(129 + NB + 1152), dim3(512), 0, stream>>>(
        e_key_W1, e_key_b1, e_key_g, e_key_be, e_key_W2, e_key_b2,
        d_key_W1, d_key_b1, d_key_g, d_key_be, d_key_W2, d_key_b2,
        enc_tbl, dec_tbl, batch, e_card_W, e_card_b, z,
        e_val_W1, evW1t, e_val_W2, evW2t, d_dec_W1, ddW1t, d_dec_W2, ddW2t,
        maxmag);
    k_mag<<<dim3(4096), dim3(256), 0, stream>>>(x, e_rank_W, e_rank_b, mag, maxmag, xb);
    k_rank<<<dim3(256), dim3(256), 0, stream>>>(batch, mag, maxmag, kidx);

    k_mm_e1f<<<dim3(512), dim3(512), 0, stream>>>(xb, evW1t, e_val_b1,
                                                  e_val_g, e_val_be, Hb);
    k_mm_e2<<<dim3(4, 512), dim3(256), 0, stream>>>(Hb, evW2t, e_val_b2, MIDV,
                                                    enc_tbl, kidx, batch, z);

    k_size<<<dim3(NB / 4), dim3(256), 0, stream>>>(z, d_size_W1, d_size_b1, d_size_g,
                                                   d_size_be, d_size_W2, d_size_b2, ndec);
    k_post<<<dim3(1024), dim3(256), 0, stream>>>(ndec, out_x, out_b, out_m,
                                                 rowmap, cntpad);
    k_mm_d1<<<dim3(3, 1024), dim3(256), 0, stream>>>(ddW1t, d_dec_b1, Hd, HIDN,
                                                     dec_tbl, z, rowmap, cntpad);
    k_mm_d2<<<dim3(2, 1024), dim3(256), 0, stream>>>(Hd, ddW2t, d_dec_b2, out_x, MIDD,
                                                     rowmap, cntpad);
}

// Round 10
// 446.604 us; speedup vs baseline: 1.1389x; 1.0850x over previous
//
#include <hip/hip_runtime.h>

#define NPTS   65536
#define NB     2048
#define DIMX   256
#define HIDN   512
#define MAXNN  64
#define MIDK   288
#define MIDV   384
#define MIDD   384
#define MIDS   256

typedef unsigned short ushort_t;
typedef __attribute__((ext_vector_type(8))) short short8;
typedef __attribute__((ext_vector_type(4))) float f32x4;

// ---------------- helpers ----------------
// mish(x) = x*tanh(softplus(x)) = x * e(e+2)/(e(e+2)+2), e = exp(x)  [exact identity]
__device__ __forceinline__ float mishf(float x) {
    float e = __expf(fminf(x, 30.f));
    float n = e * (e + 2.f);
    return x * n * __builtin_amdgcn_rcpf(n + 2.f);
}
__device__ __forceinline__ ushort_t f2bf(float f) {
    unsigned u = __float_as_uint(f);
    u += 0x7fffu + ((u >> 16) & 1u);
    return (ushort_t)(u >> 16);
}
__device__ __forceinline__ float bf2f(ushort_t h) {
    return __uint_as_float(((unsigned)h) << 16);
}
__device__ __forceinline__ void dma16(const void* g, void* lds) {
    __builtin_amdgcn_global_load_lds(
        (const __attribute__((address_space(1))) unsigned int*)g,
        (__attribute__((address_space(3))) unsigned int*)lds, 16, 0, 0);
}
__device__ __forceinline__ int lbound(const int* __restrict__ a, int lo, int hi, int v) {
    while (lo < hi) { int m = (lo + hi) >> 1; if (a[m] < v) lo = m + 1; else hi = m; }
    return lo;
}

// ---------------- merged setup ----------------
// roles by block index:
//   [0,129)            key-table MLPs (65 enc rows incl. zero-onehot, 64 dec rows)
//   [129, 129+2048)    z init with cardinality term
//   [2177, 2177+144)   LDS-tiled 64x64 weight transpose f32->bf16 (coalesced both sides)
//   [2321, 2321+2048)  mag + x->bf16 cast (8 waves/block, 4 points/wave)
#define SETUP_TBL   129
#define SETUP_Z     (SETUP_TBL + NB)          // 2177
#define SETUP_WT    (SETUP_Z + 144)           // 2321
#define SETUP_TOTAL (SETUP_WT + 2048)         // 4369

__global__ __launch_bounds__(512)
void k_setup(const float* __restrict__ eW1, const float* __restrict__ eb1,
             const float* __restrict__ eg, const float* __restrict__ ebe,
             const float* __restrict__ eW2, const float* __restrict__ eb2,
             const float* __restrict__ dW1, const float* __restrict__ db1,
             const float* __restrict__ dg, const float* __restrict__ dbe,
             const float* __restrict__ dW2, const float* __restrict__ db2,
             float* __restrict__ enc_tbl, float* __restrict__ dec_tbl,
             const int* __restrict__ batch, const float* __restrict__ cardW,
             const float* __restrict__ cardb, float* __restrict__ z,
             const float* __restrict__ V0, ushort_t* __restrict__ T0,
             const float* __restrict__ V1, ushort_t* __restrict__ T1,
             const float* __restrict__ V2, ushort_t* __restrict__ T2,
             const float* __restrict__ V3, ushort_t* __restrict__ T3,
             const float* __restrict__ x, const float* __restrict__ rW,
             const float* __restrict__ rb, float* __restrict__ mag,
             float* __restrict__ blockmax, ushort_t* __restrict__ xb)
{
    const int blk = blockIdx.x;
    const int t = threadIdx.x;
    if (blk < SETUP_TBL) {
        const float *W1, *b1, *g, *be, *W2, *b2; float* out; int wrow;
        if (blk < 65) {
            W1 = eW1; b1 = eb1; g = eg; be = ebe; W2 = eW2; b2 = eb2;
            out = enc_tbl + blk * HIDN; wrow = (blk < 64) ? blk : -1;
        } else {
            int r = blk - 65;
            W1 = dW1; b1 = db1; g = dg; be = dbe; W2 = dW2; b2 = db2;
            out = dec_tbl + r * HIDN; wrow = r;
        }
        __shared__ float h[MIDK];
        __shared__ float red[512];
        float v = 0.f;
        if (t < MIDK) v = b1[t] + (wrow >= 0 ? W1[wrow * MIDK + t] : 0.f);
        red[t] = (t < MIDK) ? v : 0.f;
        __syncthreads();
        for (int o = 256; o > 0; o >>= 1) { if (t < o) red[t] += red[t + o]; __syncthreads(); }
        float m = red[0] / (float)MIDK;
        __syncthreads();
        float d = v - m;
        red[t] = (t < MIDK) ? d * d : 0.f;
        __syncthreads();
        for (int o = 256; o > 0; o >>= 1) { if (t < o) red[t] += red[t + o]; __syncthreads(); }
        float rs = rsqrtf(red[0] / (float)MIDK + 1e-5f);
        __syncthreads();
        if (t < MIDK) h[t] = mishf(d * rs * g[t] + be[t]);
        __syncthreads();
        float acc = b2[t];
        #pragma unroll 8
        for (int k = 0; k < MIDK; ++k) acc = fmaf(h[k], W2[k * HIDN + t], acc);
        out[t] = acc;
    } else if (blk < SETUP_Z) {
        int b = blk - SETUP_TBL;
        int s = lbound(batch, 0, NPTS, b);
        int e = lbound(batch, s, NPTS, b + 1);
        float n = (float)(e - s);
        z[b * HIDN + t] = fmaf(n, cardW[t], cardb[t]);
    } else if (blk < SETUP_WT) {
        // 64x64 tile transpose through LDS; both global phases fully coalesced
        int tile = blk - SETUP_Z;
        const float* W; ushort_t* T; int K, N;
        if (tile < 24)       { W = V0; T = T0; K = 256; N = 384; }
        else if (tile < 72)  { tile -= 24;  W = V1; T = T1; K = 384; N = 512; }
        else if (tile < 120) { tile -= 72;  W = V2; T = T2; K = 512; N = 384; }
        else                 { tile -= 120; W = V3; T = T3; K = 384; N = 256; }
        int ntn = N >> 6;
        int k0 = (tile / ntn) * 64, n0 = (tile % ntn) * 64;
        __shared__ float lds[64][65];
        #pragma unroll
        for (int pass = 0; pass < 8; ++pass) {
            int kk = pass * 8 + (t >> 6);
            lds[kk][t & 63] = W[(size_t)(k0 + kk) * N + n0 + (t & 63)];
        }
        __syncthreads();
        #pragma unroll
        for (int pass = 0; pass < 8; ++pass) {
            int nn = pass * 8 + (t >> 6);
            T[(size_t)(n0 + nn) * K + k0 + (t & 63)] = f2bf(lds[t & 63][nn]);
        }
    } else {
        // mag + bf16 cast: 8 waves, 4 points per wave (stride 16384)
        int mw = blk - SETUP_WT;
        const int lane = t & 63;
        const int w = t >> 6;
        int gw = mw * 8 + w;
        float4 wv = *(const float4*)(rW + lane * 4);
        float bias = rb[0];
        float lmax = 0.f;
        for (int pt = gw; pt < NPTS; pt += 16384) {
            float4 xv = *(const float4*)(x + (size_t)pt * DIMX + lane * 4);
            ushort4 u;
            u.x = f2bf(xv.x); u.y = f2bf(xv.y); u.z = f2bf(xv.z); u.w = f2bf(xv.w);
            *(ushort4*)(xb + (size_t)pt * DIMX + lane * 4) = u;
            double d = (double)xv.x * wv.x + (double)xv.y * wv.y
                     + (double)xv.z * wv.z + (double)xv.w * wv.w;
            #pragma unroll
            for (int o = 32; o > 0; o >>= 1) d += __shfl_xor(d, o);
            float s = fabsf((float)(d + (double)bias));
            if (lane == 0) mag[pt] = s;
            lmax = fmaxf(lmax, s);
        }
        __shared__ float wm8[8];
        if (lane == 0) wm8[w] = lmax;
        __syncthreads();
        if (t == 0) {
            float m = wm8[0];
            #pragma unroll
            for (int i = 1; i < 8; ++i) m = fmaxf(m, wm8[i]);
            blockmax[mw] = m;
        }
    }
}

// rank within segment; block-reduces blockmax[2048] itself (max is exactly associative)
__global__ __launch_bounds__(256)
void k_rank(const int* __restrict__ batch, const float* __restrict__ mag,
            const float* __restrict__ blockmax, int* __restrict__ kidx)
{
    __shared__ float red[256];
    const int t = threadIdx.x;
    float m = 0.f;
    for (int i = t; i < 2048; i += 256) m = fmaxf(m, blockmax[i]);
    red[t] = m;
    __syncthreads();
    for (int o = 128; o > 0; o >>= 1) { if (t < o) red[t] = fmaxf(red[t], red[t + o]); __syncthreads(); }
    float M = red[0];

    int i = blockIdx.x * 256 + t;
    if (i >= NPTS) return;
    int b = batch[i];
    int s = lbound(batch, 0, NPTS, b);
    int e = lbound(batch, s, NPTS, b + 1);
    float kb = __fmul_rn((float)b, M);
    float ki = __fadd_rn(kb, mag[i]);
    int r = 0;
    for (int j = s; j < e; ++j) {
        float kj = __fadd_rn(kb, mag[j]);
        r += (kj < ki) || (kj == ki && j < i);
    }
    kidx[i] = (r < MAXNN) ? r : MAXNN;
}

// d_size MLP: 4 batches per block (4x W1 reuse)
__global__ __launch_bounds__(256)
void k_size(const float* __restrict__ z, const float* __restrict__ W1,
            const float* __restrict__ b1, const float* __restrict__ g,
            const float* __restrict__ be, const float* __restrict__ W2,
            const float* __restrict__ b2, int* __restrict__ ndec)
{
    const int b0 = blockIdx.x * 4, t = threadIdx.x;
    __shared__ float zr[4][HIDN];
    __shared__ float red[4][256];
    #pragma unroll
    for (int gI = 0; gI < 4; ++gI) {
        zr[gI][t] = z[(b0 + gI) * HIDN + t];
        zr[gI][t + 256] = z[(b0 + gI) * HIDN + 256 + t];
    }
    __syncthreads();
    float acc[4];
    float bb1 = b1[t];
    #pragma unroll
    for (int gI = 0; gI < 4; ++gI) acc[gI] = bb1;
    #pragma unroll 8
    for (int k = 0; k < HIDN; ++k) {
        float wv = W1[k * MIDS + t];
        #pragma unroll
        for (int gI = 0; gI < 4; ++gI) acc[gI] = fmaf(zr[gI][k], wv, acc[gI]);
    }
    #pragma unroll
    for (int gI = 0; gI < 4; ++gI) red[gI][t] = acc[gI];
    __syncthreads();
    for (int o = 128; o > 0; o >>= 1) {
        if (t < o) {
            #pragma unroll
            for (int gI = 0; gI < 4; ++gI) red[gI][t] += red[gI][t + o];
        }
        __syncthreads();
    }
    float mm[4];
    #pragma unroll
    for (int gI = 0; gI < 4; ++gI) mm[gI] = red[gI][0] * (1.f / 256.f);
    __syncthreads();
    #pragma unroll
    for (int gI = 0; gI < 4; ++gI) { float d = acc[gI] - mm[gI]; red[gI][t] = d * d; }
    __syncthreads();
    for (int o = 128; o > 0; o >>= 1) {
        if (t < o) {
            #pragma unroll
            for (int gI = 0; gI < 4; ++gI) red[gI][t] += red[gI][t + o];
        }
        __syncthreads();
    }
    float rs[4];
    #pragma unroll
    for (int gI = 0; gI < 4; ++gI) rs[gI] = rsqrtf(red[gI][0] * (1.f / 256.f) + 1e-5f);
    __syncthreads();
    float w2 = W2[t], gg = g[t], bbe = be[t];
    #pragma unroll
    for (int gI = 0; gI < 4; ++gI) {
        float h = mishf((acc[gI] - mm[gI]) * rs[gI] * gg + bbe);
        red[gI][t] = h * w2;
    }
    __syncthreads();
    for (int o = 128; o > 0; o >>= 1) {
        if (t < o) {
            #pragma unroll
            for (int gI = 0; gI < 4; ++gI) red[gI][t] += red[gI][t + o];
        }
        __syncthreads();
    }
    if (t < 4) {
        float logit = red[t][0] + b2[0];
        float n = rintf(logit);
        n = fminf(fmaxf(n, 0.f), 64.f);
        ndec[b0 + t] = (int)n;
    }
}

// zero out_x + write batch_out/mask + (block 0) compact+pad. grid 1024x256.
__global__ __launch_bounds__(256)
void k_post(const int* __restrict__ ndec, float* __restrict__ out_x,
            float* __restrict__ outb, float* __restrict__ outm,
            int* __restrict__ rowmap, int* __restrict__ cntpad)
{
    const int gidx = blockIdx.x * 256 + threadIdx.x;
    float4 z4 = make_float4(0.f, 0.f, 0.f, 0.f);
    float4* p = (float4*)out_x;
    #pragma unroll
    for (int i = 0; i < 32; ++i) p[gidx + i * 262144] = z4;
    if (gidx < NB * MAXNN) {
        outb[gidx] = (float)(gidx >> 6);
        outm[gidx] = ((gidx & 63) < ndec[gidx >> 6]) ? 1.f : 0.f;
    }
    if (blockIdx.x == 0) {
        __shared__ int lcnt;
        if (threadIdx.x == 0) lcnt = 0;
        __syncthreads();
        for (int b = threadIdx.x; b < NB; b += 256) {
            int n = ndec[b];
            if (n > 0) {
                int base = atomicAdd(&lcnt, n);
                for (int q = 0; q < n; ++q) rowmap[base + q] = b * 64 + q;
            }
        }
        __syncthreads();
        int c = lcnt;
        int pad = (c + 127) & ~127;
        for (int i = c + threadIdx.x; i < pad; i += 256) rowmap[i] = -1;
        if (threadIdx.x == 0) *cntpad = pad;
    }
}

// ---------------- E1 fused: Hb = bf16(mish(LN(xb @ W1t + b1))) ----------------
__global__ __launch_bounds__(512, 2)
void k_mm_e1f(const ushort_t* __restrict__ A, const ushort_t* __restrict__ Bt,
              const float* __restrict__ bias, const float* __restrict__ g,
              const float* __restrict__ be, ushort_t* __restrict__ C)
{
    const int m0 = blockIdx.x * 128;
    __shared__ __align__(16) ushort_t As[128 * 64];    // 16 KB
    __shared__ __align__(16) ushort_t Bs[384 * 64];    // 48 KB
    const int t = threadIdx.x;
    const int l = t & 63;
    const int w = t >> 6;
    const int wm = (w >> 2) * 64;
    const int wq = (w & 3) * 96;
    const int l4 = (l >> 4) << 2;
    const int drow = l >> 3;
    const int dblk = (l & 7) ^ drow;

    f32x4 acc[4][6];
    #pragma unroll
    for (int a = 0; a < 4; ++a)
        #pragma unroll
        for (int b = 0; b < 6; ++b) acc[a][b] = (f32x4)0.f;

    for (int k0 = 0; k0 < DIMX; k0 += 64) {
        #pragma unroll
        for (int ii = 0; ii < 2; ++ii) {
            int i = w * 2 + ii;
            dma16(A + (size_t)(m0 + i * 8 + drow) * DIMX + k0 + dblk * 8, &As[i * 512]);
        }
        #pragma unroll
        for (int ii = 0; ii < 6; ++ii) {
            int i = w * 6 + ii;
            dma16(Bt + (size_t)(i * 8 + drow) * DIMX + k0 + dblk * 8, &Bs[i * 512]);
        }
        __syncthreads();
        #pragma unroll
        for (int ks = 0; ks < 2; ++ks) {
            int kq = ks * 4 + (l >> 4);
            short8 af[4], bfr[6];
            #pragma unroll
            for (int fm = 0; fm < 4; ++fm) {
                int row = wm + fm * 16 + (l & 15);
                af[fm] = *(const short8*)&As[row * 64 + ((kq ^ (row & 7)) << 3)];
            }
            #pragma unroll
            for (int fn = 0; fn < 6; ++fn) {
                int row = wq + fn * 16 + (l & 15);
                bfr[fn] = *(const short8*)&Bs[row * 64 + ((kq ^ (row & 7)) << 3)];
            }
            #pragma unroll
            for (int fm = 0; fm < 4; ++fm)
                #pragma unroll
                for (int fn = 0; fn < 6; ++fn)
                    acc[fm][fn] = __builtin_amdgcn_mfma_f32_16x16x32_bf16(
                        af[fm], bfr[fn], acc[fm][fn], 0, 0, 0);
        }
        __syncthreads();
    }

    float bb[6], gg[6], bee[6];
    #pragma unroll
    for (int fn = 0; fn < 6; ++fn) {
        int col = wq + fn * 16 + (l & 15);
        bb[fn] = bias[col]; gg[fn] = g[col]; bee[fn] = be[col];
    }
    #pragma unroll
    for (int fm = 0; fm < 4; ++fm)
        #pragma unroll
        for (int fn = 0; fn < 6; ++fn)
            #pragma unroll
            for (int j = 0; j < 4; ++j) acc[fm][fn][j] += bb[fn];

    float* ssum = (float*)As;
    float* ssq  = ssum + 512;
    #pragma unroll
    for (int fm = 0; fm < 4; ++fm) {
        #pragma unroll
        for (int j = 0; j < 4; ++j) {
            float s = 0.f, q = 0.f;
            #pragma unroll
            for (int fn = 0; fn < 6; ++fn) {
                float v = acc[fm][fn][j];
                s += v; q += v * v;
            }
            #pragma unroll
            for (int o = 1; o < 16; o <<= 1) {
                s += __shfl_xor(s, o);
                q += __shfl_xor(q, o);
            }
            if ((l & 15) == 0) {
                int r = wm + fm * 16 + l4 + j;
                ssum[r * 4 + (w & 3)] = s;
                ssq[r * 4 + (w & 3)] = q;
            }
        }
    }
    __syncthreads();
    #pragma unroll
    for (int fm = 0; fm < 4; ++fm) {
        #pragma unroll
        for (int j = 0; j < 4; ++j) {
            int r = wm + fm * 16 + l4 + j;
            float s = ssum[r * 4 + 0] + ssum[r * 4 + 1] + ssum[r * 4 + 2] + ssum[r * 4 + 3];
            float q = ssq[r * 4 + 0] + ssq[r * 4 + 1] + ssq[r * 4 + 2] + ssq[r * 4 + 3];
            float m = s * (1.f / 384.f);
            float var = q * (1.f / 384.f) - m * m;
            float rs = rsqrtf(var + 1e-5f);
            #pragma unroll
            for (int fn = 0; fn < 6; ++fn) {
                float v = (acc[fm][fn][j] - m) * rs * gg[fn] + bee[fn];
                C[(size_t)(m0 + r) * MIDV + wq + fn * 16 + (l & 15)] = f2bf(mishf(v));
            }
        }
    }
}

// ---------------- E2: (Hb @ W2t + b2) * enc_tbl[kidx]; segmented scan -> atomicAdd z ----
__global__ __launch_bounds__(256, 2)
void k_mm_e2(const ushort_t* __restrict__ A, const ushort_t* __restrict__ Bt,
             const float* __restrict__ bias, int K, const float* __restrict__ tbl,
             const int* __restrict__ kidx, const int* __restrict__ batch,
             float* __restrict__ zout)
{
    const int flat = blockIdx.y * gridDim.x + blockIdx.x;
    const int nx = gridDim.x;
    const int xcd = flat & 7;
    const int lin = flat >> 3;
    const int n0 = (lin % nx) * 128;
    const int m0 = ((lin / nx) + ((gridDim.y >> 3) * xcd)) * 128;
    __shared__ __align__(16) ushort_t sAB[2 * 128 * 64];
    __shared__ int barr[128];
    __shared__ int karr[128];
    ushort_t* As = sAB;
    ushort_t* Bs = sAB + 128 * 64;
    const int t = threadIdx.x;
    const int l = t & 63;
    const int w = t >> 6;
    const int wm = (w >> 1) * 64;
    const int wn = (w & 1) * 64;
    const int l4 = (l >> 4) << 2;
    const int drow = l >> 3;
    const int dblk = (l & 7) ^ drow;

    if (t < 128) { barr[t] = batch[m0 + t]; karr[t] = kidx[m0 + t]; }

    f32x4 acc[4][4];
    #pragma unroll
    for (int a = 0; a < 4; ++a)
        #pragma unroll
        for (int b = 0; b < 4; ++b) acc[a][b] = (f32x4)0.f;

    for (int k0 = 0; k0 < K; k0 += 64) {
        #pragma unroll
        for (int ii = 0; ii < 4; ++ii) {
            int i = w * 4 + ii;
            dma16(A + (size_t)(m0 + i * 8 + drow) * K + k0 + dblk * 8, &As[i * 512]);
        }
        #pragma unroll
        for (int ii = 0; ii < 4; ++ii) {
            int i = w * 4 + ii;
            dma16(Bt + (size_t)(n0 + i * 8 + drow) * K + k0 + dblk * 8, &Bs[i * 512]);
        }
        __syncthreads();
        #pragma unroll
        for (int ks = 0; ks < 2; ++ks) {
            short8 af[4], bfr[4];
            int kq = ks * 4 + (l >> 4);
            #pragma unroll
            for (int fm = 0; fm < 4; ++fm) {
                int row = wm + fm * 16 + (l & 15);
                af[fm] = *(const short8*)&As[row * 64 + ((kq ^ (row & 7)) << 3)];
            }
            #pragma unroll
            for (int fn = 0; fn < 4; ++fn) {
                int row = wn + fn * 16 + (l & 15);
                bfr[fn] = *(const short8*)&Bs[row * 64 + ((kq ^ (row & 7)) << 3)];
            }
            #pragma unroll
            for (int fm = 0; fm < 4; ++fm)
                #pragma unroll
                for (int fn = 0; fn < 4; ++fn)
                    acc[fm][fn] = __builtin_amdgcn_mfma_f32_16x16x32_bf16(
                        af[fm], bfr[fn], acc[fm][fn], 0, 0, 0);
        }
        __syncthreads();
    }

    float* yred = (float*)sAB;     // 128 cols x 64 rows
    #pragma unroll
    for (int pass = 0; pass < 2; ++pass) {
        if ((w >> 1) == pass) {
            #pragma unroll
            for (int fn = 0; fn < 4; ++fn) {
                int cl = wn + fn * 16 + (l & 15);
                float bbv = bias[n0 + cl];
                #pragma unroll
                for (int fm = 0; fm < 4; ++fm) {
                    #pragma unroll
                    for (int j = 0; j < 4; ++j) {
                        int rl = fm * 16 + l4 + j;
                        float v = (acc[fm][fn][j] + bbv)
                                * tbl[karr[pass * 64 + rl] * HIDN + (n0 + cl)];
                        yred[cl * 64 + (rl ^ (cl & 31))] = v;
                    }
                }
            }
        }
        __syncthreads();
        {
            int c = t & 127, q = t >> 7;
            int gc = n0 + c;
            float run = 0.f; int curb = -1;
            #pragma unroll
            for (int ch = 0; ch < 2; ++ch) {
                float v16[16]; int b16[16];
                #pragma unroll
                for (int rr = 0; rr < 16; ++rr) {
                    int rl = q * 32 + ch * 16 + rr;
                    v16[rr] = yred[c * 64 + (rl ^ (c & 31))];
                    b16[rr] = barr[pass * 64 + rl];
                }
                #pragma unroll
                for (int rr = 0; rr < 16; ++rr) {
                    if (b16[rr] != curb) {
                        if (curb >= 0) atomicAdd(&zout[curb * HIDN + gc], run);
                        curb = b16[rr]; run = v16[rr];
                    } else run += v16[rr];
                }
            }
            atomicAdd(&zout[curb * HIDN + gc], run);
        }
        __syncthreads();
    }
}

// ---------------- decoder GEMMs (modes 2,3) ----------------
template<int MODE>
__device__ __forceinline__
void mm_body(const ushort_t* __restrict__ A, const ushort_t* __restrict__ Bt,
             const float* __restrict__ bias, void* __restrict__ Cptr, int K,
             const float* __restrict__ tbl, const float* __restrict__ zin,
             const int* __restrict__ rowmap, const int* __restrict__ cntpad)
{
    const int flat = blockIdx.y * gridDim.x + blockIdx.x;
    const int nx = gridDim.x;
    const int xcd = flat & 7;
    const int lin = flat >> 3;
    const int n0 = (lin % nx) * 128;
    const int m0 = ((lin / nx) + ((gridDim.y >> 3) * xcd)) * 128;
    if (m0 >= *cntpad) return;
    __shared__ __align__(16) ushort_t sAB[2 * 128 * 64];
    ushort_t* As = sAB;
    ushort_t* Bs = sAB + 128 * 64;
    const int t = threadIdx.x;
    const int l = t & 63;
    const int w = t >> 6;
    const int wm = (w >> 1) * 64;
    const int wn = (w & 1) * 64;
    const int l4 = (l >> 4) << 2;
    const int drow = l >> 3;
    const int dblk = (l & 7) ^ drow;

    int g4[4], p4[4];
    if (MODE == 2) {
        #pragma unroll
        for (int ii = 0; ii < 4; ++ii) {
            int i = w * 4 + ii;
            int gr = rowmap[m0 + i * 8 + drow];
            if (gr < 0) gr = 0;
            g4[ii] = gr >> 6; p4[ii] = gr & 63;
        }
    }

    f32x4 acc[4][4];
    #pragma unroll
    for (int a = 0; a < 4; ++a)
        #pragma unroll
        for (int b = 0; b < 4; ++b) acc[a][b] = (f32x4)0.f;

    for (int k0 = 0; k0 < K; k0 += 64) {
        if (MODE == 2) {
            #pragma unroll
            for (int ii = 0; ii < 4; ++ii) {
                int i = w * 4 + ii;
                int row = i * 8 + drow;
                const float* zp = zin + g4[ii] * HIDN + k0 + dblk * 8;
                const float* kp = tbl + p4[ii] * HIDN + k0 + dblk * 8;
                float4 z0 = *(const float4*)zp;
                float4 z1 = *(const float4*)(zp + 4);
                float4 q0 = *(const float4*)kp;
                float4 q1 = *(const float4*)(kp + 4);
                ushort4 u0, u1;
                u0.x = f2bf(z0.x * q0.x); u0.y = f2bf(z0.y * q0.y);
                u0.z = f2bf(z0.z * q0.z); u0.w = f2bf(z0.w * q0.w);
                u1.x = f2bf(z1.x * q1.x); u1.y = f2bf(z1.y * q1.y);
                u1.z = f2bf(z1.z * q1.z); u1.w = f2bf(z1.w * q1.w);
                ushort_t* dst = &As[row * 64 + (l & 7) * 8];
                *(ushort4*)dst = u0;
                *(ushort4*)(dst + 4) = u1;
            }
        } else {
            #pragma unroll
            for (int ii = 0; ii < 4; ++ii) {
                int i = w * 4 + ii;
                const ushort_t* gp = A + (size_t)(m0 + i * 8 + drow) * K + k0 + dblk * 8;
                dma16(gp, &As[i * 512]);
            }
        }
        #pragma unroll
        for (int ii = 0; ii < 4; ++ii) {
            int i = w * 4 + ii;
            const ushort_t* gp = Bt + (size_t)(n0 + i * 8 + drow) * K + k0 + dblk * 8;
            dma16(gp, &Bs[i * 512]);
        }
        __syncthreads();
        #pragma unroll
        for (int ks = 0; ks < 2; ++ks) {
            short8 af[4], bfr[4];
            int kq = ks * 4 + (l >> 4);
            #pragma unroll
            for (int fm = 0; fm < 4; ++fm) {
                int row = wm + fm * 16 + (l & 15);
                af[fm] = *(const short8*)&As[row * 64 + ((kq ^ (row & 7)) << 3)];
            }
            #pragma unroll
            for (int fn = 0; fn < 4; ++fn) {
                int row = wn + fn * 16 + (l & 15);
                bfr[fn] = *(const short8*)&Bs[row * 64 + ((kq ^ (row & 7)) << 3)];
            }
            #pragma unroll
            for (int fm = 0; fm < 4; ++fm)
                #pragma unroll
                for (int fn = 0; fn < 4; ++fn)
                    acc[fm][fn] = __builtin_amdgcn_mfma_f32_16x16x32_bf16(
                        af[fm], bfr[fn], acc[fm][fn], 0, 0, 0);
        }
        __syncthreads();
    }

    if (MODE == 2) {
        ushort_t* C = (ushort_t*)Cptr;
        #pragma unroll
        for (int fm = 0; fm < 4; ++fm) {
            int gr0 = m0 + wm + fm * 16 + l4;
            #pragma unroll
            for (int fn = 0; fn < 4; ++fn) {
                int gc = n0 + wn + fn * 16 + (l & 15);
                float bbv = bias[gc];
                #pragma unroll
                for (int j = 0; j < 4; ++j)
                    C[(size_t)(gr0 + j) * MIDD + gc] = f2bf(mishf(acc[fm][fn][j] + bbv));
            }
        }
    } else {
        float* C = (float*)Cptr;
        #pragma unroll
        for (int fm = 0; fm < 4; ++fm) {
            int gr0 = m0 + wm + fm * 16 + l4;
            int om[4];
            #pragma unroll
            for (int j = 0; j < 4; ++j) om[j] = rowmap[gr0 + j];
            #pragma unroll
            for (int fn = 0; fn < 4; ++fn) {
                int gc = n0 + wn + fn * 16 + (l & 15);
                float bbv = bias[gc];
                #pragma unroll
                for (int j = 0; j < 4; ++j)
                    if (om[j] >= 0) C[(size_t)om[j] * DIMX + gc] = acc[fm][fn][j] + bbv;
            }
        }
    }
}

__global__ __launch_bounds__(256, 2)
void k_mm_d1(const ushort_t* Bt, const float* bias, void* C, int K,
             const float* tbl, const float* zin, const int* rowmap, const int* cntpad)
{ mm_body<2>(nullptr, Bt, bias, C, K, tbl, zin, rowmap, cntpad); }

__global__ __launch_bounds__(256, 2)
void k_mm_d2(const ushort_t* A, const ushort_t* Bt, const float* bias, void* C, int K,
             const int* rowmap, const int* cntpad)
{ mm_body<3>(A, Bt, bias, C, K, nullptr, nullptr, rowmap, cntpad); }

// ---------------- launch ----------------
extern "C" void kernel_launch(void* const* d_in, const int* in_sizes, int n_in,
                              void* d_out, int out_size, void* d_ws, size_t ws_size,
                              hipStream_t stream)
{
    const float* x        = (const float*)d_in[0];
    const int*   batch    = (const int*)  d_in[1];
    const float* e_rank_W = (const float*)d_in[3];
    const float* e_rank_b = (const float*)d_in[4];
    const float* e_card_W = (const float*)d_in[5];
    const float* e_card_b = (const float*)d_in[6];
    const float* e_key_W1 = (const float*)d_in[7];
    const float* e_key_b1 = (const float*)d_in[8];
    const float* e_key_g  = (const float*)d_in[9];
    const float* e_key_be = (const float*)d_in[10];
    const float* e_key_W2 = (const float*)d_in[11];
    const float* e_key_b2 = (const float*)d_in[12];
    const float* e_val_W1 = (const float*)d_in[13];
    const float* e_val_b1 = (const float*)d_in[14];
    const float* e_val_g  = (const float*)d_in[15];
    const float* e_val_be = (const float*)d_in[16];
    const float* e_val_W2 = (const float*)d_in[17];
    const float* e_val_b2 = (const float*)d_in[18];
    const float* d_key_W1 = (const float*)d_in[19];
    const float* d_key_b1 = (const float*)d_in[20];
    const float* d_key_g  = (const float*)d_in[21];
    const float* d_key_be = (const float*)d_in[22];
    const float* d_key_W2 = (const float*)d_in[23];
    const float* d_key_b2 = (const float*)d_in[24];
    const float* d_dec_W1 = (const float*)d_in[25];
    const float* d_dec_b1 = (const float*)d_in[26];
    const float* d_dec_W2 = (const float*)d_in[27];
    const float* d_dec_b2 = (const float*)d_in[28];
    const float* d_size_W1= (const float*)d_in[29];
    const float* d_size_b1= (const float*)d_in[30];
    const float* d_size_g = (const float*)d_in[31];
    const float* d_size_be= (const float*)d_in[32];
    const float* d_size_W2= (const float*)d_in[33];
    const float* d_size_b2= (const float*)d_in[34];

    char* ws = (char*)d_ws;
    float*        blockmax= (float*)       (ws + 0);          // 2048*4
    int*          kidx    = (int*)         (ws + 8704);
    float*        mag     = (float*)       (ws + 270848);
    float*        enc_tbl = (float*)       (ws + 532992);
    float*        dec_tbl = (float*)       (ws + 666112);
    float*        z       = (float*)       (ws + 797184);
    int*          ndec    = (int*)         (ws + 4991488);
    int*          cntpad  = (int*)         (ws + 4999684);
    int*          rowmap  = (int*)         (ws + 5000192);
    ushort_t*     evW1t   = (ushort_t*)    (ws + 5524480);
    ushort_t*     evW2t   = (ushort_t*)    (ws + 5721088);
    ushort_t*     ddW1t   = (ushort_t*)    (ws + 6114304);
    ushort_t*     ddW2t   = (ushort_t*)    (ws + 6507520);
    ushort_t*     xb      = (ushort_t*)    (ws + 6704384);              // 32 MB
    ushort_t*     Hb      = (ushort_t*)    (ws + 6704384 + 33554432);   // 48 MB (aliases Hd)
    ushort_t*     Hd      = (ushort_t*)    (ws + 6704384 + 33554432);   // 96 MB

    float* out_x = (float*)d_out;
    float* out_b = out_x + (size_t)NB * MAXNN * DIMX;
    float* out_m = out_b + NB * MAXNN;

    k_setup<<<dim3(SETUP_TOTAL), dim3(512), 0, stream>>>(
        e_key_W1, e_key_b1, e_key_g, e_key_be, e_key_W2, e_key_b2,
        d_key_W1, d_key_b1, d_key_g, d_key_be, d_key_W2, d_key_b2,
        enc_tbl, dec_tbl, batch, e_card_W, e_card_b, z,
        e_val_W1, evW1t, e_val_W2, evW2t, d_dec_W1, ddW1t, d_dec_W2, ddW2t,
        x, e_rank_W, e_rank_b, mag, blockmax, xb);
    k_rank<<<dim3(256), dim3(256), 0, stream>>>(batch, mag, blockmax, kidx);

    k_mm_e1f<<<dim3(512), dim3(512), 0, stream>>>(xb, evW1t, e_val_b1,
                                                  e_val_g, e_val_be, Hb);
    k_mm_e2<<<dim3(4, 512), dim3(256), 0, stream>>>(Hb, evW2t, e_val_b2, MIDV,
                                                    enc_tbl, kidx, batch, z);

    k_size<<<dim3(NB / 4), dim3(256), 0, stream>>>(z, d_size_W1, d_size_b1, d_size_g,
                                                   d_size_be, d_size_W2, d_size_b2, ndec);
    k_post<<<dim3(1024), dim3(256), 0, stream>>>(ndec, out_x, out_b, out_m,
                                                 rowmap, cntpad);
    k_mm_d1<<<dim3(3, 1024), dim3(256), 0, stream>>>(ddW1t, d_dec_b1, Hd, HIDN,
                                                     dec_tbl, z, rowmap, cntpad);
    k_mm_d2<<<dim3(2, 1024), dim3(256), 0, stream>>>(Hd, ddW2t, d_dec_b2, out_x, MIDD,
                                                     rowmap, cntpad);
}